// Round 1
// baseline (2016.670 us; speedup 1.0000x reference)
//
#include <hip/hip_runtime.h>
#include <cstdint>
#include <cstddef>

#define N_NODES 50000
#define N_EDGES 800000
#define N_GRAPH 256
#define Z_DIM   2304

static constexpr float LEAKY  = 0.01f;
static constexpr float BN_EPS = 1e-5f;

// ---------------- CSR build ----------------

__global__ void hist_kernel(const int* __restrict__ idx, int* __restrict__ cnt, int n) {
  int i = blockIdx.x * blockDim.x + threadIdx.x;
  if (i < n) atomicAdd(&cnt[idx[i]], 1);
}

// single-block exclusive scan, out[n] = total
__global__ __launch_bounds__(1024) void scan_kernel(const int* __restrict__ in,
                                                    int* __restrict__ out, int n) {
  __shared__ int smem[1024];
  __shared__ int carry_s;
  if (threadIdx.x == 0) carry_s = 0;
  __syncthreads();
  for (int base = 0; base < n; base += 1024) {
    int i = base + (int)threadIdx.x;
    int v = (i < n) ? in[i] : 0;
    smem[threadIdx.x] = v;
    __syncthreads();
    for (int off = 1; off < 1024; off <<= 1) {
      int t = (threadIdx.x >= (unsigned)off) ? smem[threadIdx.x - off] : 0;
      __syncthreads();
      smem[threadIdx.x] += t;
      __syncthreads();
    }
    if (i < n) out[i] = carry_s + smem[threadIdx.x] - v;
    __syncthreads();
    if (threadIdx.x == 1023) carry_s += smem[1023];
    __syncthreads();
  }
  if (threadIdx.x == 0) out[n] = carry_s;
}

__global__ void bucket_kernel(const int* __restrict__ src, const int* __restrict__ dst,
                              const float* __restrict__ ew, const int* __restrict__ rowptr,
                              int* __restrict__ cursor, int* __restrict__ esrc,
                              float* __restrict__ eww, int E) {
  int e = blockIdx.x * blockDim.x + threadIdx.x;
  if (e < E) {
    int d = dst[e];
    int p = rowptr[d] + atomicAdd(&cursor[d], 1);
    esrc[p] = src[e];
    eww[p]  = ew[e];
  }
}

// ---------------- aggregation: one wave per dst node ----------------

template <int D>
__global__ void agg_kernel(const float* __restrict__ h, const int* __restrict__ rowptr,
                           const int* __restrict__ esrc, const float* __restrict__ eww,
                           float* __restrict__ agg) {
  int gid  = blockIdx.x * blockDim.x + threadIdx.x;
  int node = gid >> 6;
  int lane = threadIdx.x & 63;
  if (node >= N_NODES) return;
  int beg = rowptr[node], end = rowptr[node + 1];
  float acc[D / 64];
#pragma unroll
  for (int i = 0; i < D / 64; ++i) acc[i] = 0.f;
  for (int p = beg; p < end; ++p) {
    int   s = esrc[p];
    float w = eww[p];
    const float* row = h + (size_t)s * D;
#pragma unroll
    for (int i = 0; i < D / 64; ++i) acc[i] += row[lane + 64 * i] * w;
  }
  float* o = agg + (size_t)node * D;
#pragma unroll
  for (int i = 0; i < D / 64; ++i) o[lane + 64 * i] = acc[i];
}

// ---------------- fused dual GEMM: out = A1@W1 + A2@W2 + b, then leaky ----------------
// A1,A2: [M,K] row-major; W1,W2: [K,N] row-major; 64x64 tile, BK=16, 4x4/thread.

__global__ __launch_bounds__(256) void gemm_dual_kernel(
    const float* __restrict__ A1, const float* __restrict__ A2,
    const float* __restrict__ W1, const float* __restrict__ W2,
    const float* __restrict__ bias, float* __restrict__ out,
    int M, int K, int N) {
  __shared__ float As1[16][68];
  __shared__ float As2[16][68];
  __shared__ float Bs1[16][64];
  __shared__ float Bs2[16][64];

  const int m0 = blockIdx.x * 64;
  const int n0 = blockIdx.y * 64;
  const int t  = threadIdx.x;
  const int tx = t & 15, ty = t >> 4;

  // loader mapping
  const int lm  = t >> 2;         // 0..63   A row within tile
  const int lk4 = (t & 3) * 4;    // 0,4,8,12 A k offset (float4)
  const int lbk = t >> 4;         // 0..15   W k row
  const int lbn = (t & 15) * 4;   // W n offset (float4)

  float acc[4][4];
#pragma unroll
  for (int i = 0; i < 4; ++i)
#pragma unroll
    for (int j = 0; j < 4; ++j) acc[i][j] = 0.f;

  for (int k0 = 0; k0 < K; k0 += 16) {
    const int row = m0 + lm;
    float4 a1, a2;
    if (row < M) {
      a1 = *(const float4*)(A1 + (size_t)row * K + k0 + lk4);
      a2 = *(const float4*)(A2 + (size_t)row * K + k0 + lk4);
    } else {
      a1 = make_float4(0.f, 0.f, 0.f, 0.f);
      a2 = a1;
    }
    const float4 b1 = *(const float4*)(W1 + (size_t)(k0 + lbk) * N + n0 + lbn);
    const float4 b2 = *(const float4*)(W2 + (size_t)(k0 + lbk) * N + n0 + lbn);

    __syncthreads();  // previous tile fully consumed
    As1[lk4 + 0][lm] = a1.x; As1[lk4 + 1][lm] = a1.y;
    As1[lk4 + 2][lm] = a1.z; As1[lk4 + 3][lm] = a1.w;
    As2[lk4 + 0][lm] = a2.x; As2[lk4 + 1][lm] = a2.y;
    As2[lk4 + 2][lm] = a2.z; As2[lk4 + 3][lm] = a2.w;
    *(float4*)&Bs1[lbk][lbn] = b1;
    *(float4*)&Bs2[lbk][lbn] = b2;
    __syncthreads();

#pragma unroll
    for (int k = 0; k < 16; ++k) {
      const float4 a1v = *(const float4*)&As1[k][ty * 4];
      const float4 a2v = *(const float4*)&As2[k][ty * 4];
      const float4 b1v = *(const float4*)&Bs1[k][tx * 4];
      const float4 b2v = *(const float4*)&Bs2[k][tx * 4];
      const float a1r[4] = {a1v.x, a1v.y, a1v.z, a1v.w};
      const float a2r[4] = {a2v.x, a2v.y, a2v.z, a2v.w};
      const float b1r[4] = {b1v.x, b1v.y, b1v.z, b1v.w};
      const float b2r[4] = {b2v.x, b2v.y, b2v.z, b2v.w};
#pragma unroll
      for (int i = 0; i < 4; ++i)
#pragma unroll
        for (int j = 0; j < 4; ++j)
          acc[i][j] += a1r[i] * b1r[j] + a2r[i] * b2r[j];
    }
  }

  const float4 bv = *(const float4*)(bias + n0 + tx * 4);
  const float bb[4] = {bv.x, bv.y, bv.z, bv.w};
#pragma unroll
  for (int i = 0; i < 4; ++i) {
    const int row = m0 + ty * 4 + i;
    if (row < M) {
      float4 o;
      float v;
      v = acc[i][0] + bb[0]; o.x = v > 0.f ? v : LEAKY * v;
      v = acc[i][1] + bb[1]; o.y = v > 0.f ? v : LEAKY * v;
      v = acc[i][2] + bb[2]; o.z = v > 0.f ? v : LEAKY * v;
      v = acc[i][3] + bb[3]; o.w = v > 0.f ? v : LEAKY * v;
      *(float4*)(out + (size_t)row * N + n0 + tx * 4) = o;
    }
  }
}

// ---------------- BatchNorm (training mode) ----------------

// sums[0..C) = column sums, sums[C..2C) = column sum-of-squares
__global__ __launch_bounds__(128) void bn_stats_kernel(const float* __restrict__ h,
                                                       float* __restrict__ sums,
                                                       int n, int C) {
  const int c = blockIdx.x * 128 + threadIdx.x;
  const int nb = gridDim.y;
  const int rows_per = (n + nb - 1) / nb;
  const int r0 = blockIdx.y * rows_per;
  const int r1 = min(n, r0 + rows_per);
  float s = 0.f, ss = 0.f;
  for (int r = r0; r < r1; ++r) {
    const float v = h[(size_t)r * C + c];
    s += v;
    ss += v * v;
  }
  atomicAdd(&sums[c], s);
  atomicAdd(&sums[C + c], ss);
}

__global__ void bn_apply_kernel(float* __restrict__ h, const float* __restrict__ sums,
                                const float* __restrict__ gamma, const float* __restrict__ beta,
                                int n, int C) {
  const int i = blockIdx.x * blockDim.x + threadIdx.x;
  const int total = n * C;
  if (i >= total) return;
  const int c = i % C;
  const float inv_n = 1.f / (float)n;
  const float mu  = sums[c] * inv_n;
  const float var = sums[C + c] * inv_n - mu * mu;
  const float sc  = rsqrtf(var + BN_EPS) * gamma[c];
  h[i] = (h[i] - mu) * sc + beta[c];
}

// ---------------- pooling (max | mean | sum) per graph ----------------

__global__ __launch_bounds__(128) void pool_kernel(const float* __restrict__ h,
                                                   const int* __restrict__ gptr,
                                                   float* __restrict__ z, int C, int zoff) {
  const int g = blockIdx.x;
  const int beg = gptr[g], end = gptr[g + 1];
  const int cnt = end - beg;
  for (int c = threadIdx.x; c < C; c += 128) {
    float mx = -3.4e38f, s = 0.f;
    for (int r = beg; r < end; ++r) {
      const float v = h[(size_t)r * C + c];
      mx = fmaxf(mx, v);
      s += v;
    }
    const float mean = s / (float)(cnt > 0 ? cnt : 1);
    if (cnt == 0) mx = 0.f;
    float* zg = z + (size_t)g * Z_DIM + zoff;
    zg[c]         = mx;
    zg[C + c]     = mean;
    zg[2 * C + c] = s;
  }
}

// ---------------- FC head: relu(z@W1+b1) -> relu(@W2+b2) -> @W3+b3 -> log_softmax ----------------

__global__ __launch_bounds__(128) void fc_kernel(const float* __restrict__ z,
                                                 const float* __restrict__ w1, const float* __restrict__ b1,
                                                 const float* __restrict__ w2, const float* __restrict__ b2,
                                                 const float* __restrict__ w3, const float* __restrict__ b3,
                                                 float* __restrict__ out) {
  __shared__ float zs[Z_DIM];
  __shared__ float h1[128];
  __shared__ float red[128][2];
  __shared__ float y2[2];
  const int g = blockIdx.x;
  const int t = threadIdx.x;
  for (int i = t; i < Z_DIM; i += 128) zs[i] = z[(size_t)g * Z_DIM + i];
  __syncthreads();

  float acc = b1[t];
  for (int k = 0; k < Z_DIM; ++k) acc += zs[k] * w1[(size_t)k * 128 + t];
  h1[t] = fmaxf(acc, 0.f);
  __syncthreads();

  red[t][0] = h1[t] * w2[t * 2 + 0];
  red[t][1] = h1[t] * w2[t * 2 + 1];
  __syncthreads();
  if (t < 2) {
    float s = b2[t];
    for (int k = 0; k < 128; ++k) s += red[k][t];
    y2[t] = fmaxf(s, 0.f);
  }
  __syncthreads();
  if (t == 0) {
    const float z0 = y2[0] * w3[0] + y2[1] * w3[2] + b3[0];
    const float z1 = y2[0] * w3[1] + y2[1] * w3[3] + b3[1];
    const float m  = fmaxf(z0, z1);
    const float lse = m + logf(expf(z0 - m) + expf(z1 - m));
    out[g * 2 + 0] = z0 - lse;
    out[g * 2 + 1] = z1 - lse;
  }
}

// ---------------- launch ----------------

extern "C" void kernel_launch(void* const* d_in, const int* in_sizes, int n_in,
                              void* d_out, int out_size, void* d_ws, size_t ws_size,
                              hipStream_t stream) {
  (void)in_sizes; (void)n_in; (void)out_size; (void)ws_size;
  const float* x        = (const float*)d_in[0];
  const int*   eidx     = (const int*)d_in[1];
  const int*   batch    = (const int*)d_in[2];
  const float* eattr    = (const float*)d_in[3];
  const float* w_rel1   = (const float*)d_in[4];
  const float* b_rel1   = (const float*)d_in[5];
  const float* w_root1  = (const float*)d_in[6];
  const float* w_rel2   = (const float*)d_in[7];
  const float* b_rel2   = (const float*)d_in[8];
  const float* w_root2  = (const float*)d_in[9];
  const float* w_rel3   = (const float*)d_in[10];
  const float* b_rel3   = (const float*)d_in[11];
  const float* w_root3  = (const float*)d_in[12];
  const float* gamma1   = (const float*)d_in[13];
  const float* beta1    = (const float*)d_in[14];
  const float* gamma2   = (const float*)d_in[15];
  const float* beta2    = (const float*)d_in[16];
  const float* gamma3   = (const float*)d_in[17];
  const float* beta3    = (const float*)d_in[18];
  const float* w_lin1   = (const float*)d_in[19];
  const float* b_lin1   = (const float*)d_in[20];
  const float* w_lin2   = (const float*)d_in[21];
  const float* b_lin2   = (const float*)d_in[22];
  const float* w_lin3   = (const float*)d_in[23];
  const float* b_lin3   = (const float*)d_in[24];

  const int* src = eidx;
  const int* dst = eidx + N_EDGES;
  float* outp = (float*)d_out;

  // workspace carve-up (256B aligned chunks)
  char* ws = (char*)d_ws;
  size_t off = 0;
  auto alloc = [&](size_t bytes) -> void* {
    void* p = ws + off;
    off += (bytes + 255) & ~(size_t)255;
    return p;
  };
  int*   rowptr = (int*)alloc((N_NODES + 1) * sizeof(int));
  int*   cursor = (int*)alloc(N_NODES * sizeof(int));      // also deg
  int*   gptr   = (int*)alloc((N_GRAPH + 1) * sizeof(int));
  int*   gcnt   = (int*)alloc(N_GRAPH * sizeof(int));
  int*   esrc   = (int*)alloc(N_EDGES * sizeof(int));
  float* eww    = (float*)alloc(N_EDGES * sizeof(float));
  float* sums   = (float*)alloc(2 * 384 * sizeof(float));
  float* zbuf   = (float*)alloc((size_t)N_GRAPH * Z_DIM * sizeof(float));
  float* bufA   = (float*)alloc((size_t)N_NODES * 384 * sizeof(float));
  float* bufB   = (float*)alloc((size_t)N_NODES * 384 * sizeof(float));
  float* bufC   = (float*)alloc((size_t)N_NODES * 256 * sizeof(float));

  const int EB = (N_EDGES + 255) / 256;
  const int NB = (N_NODES + 255) / 256;

  // ---- CSR by dst ----
  hipMemsetAsync(cursor, 0, N_NODES * sizeof(int), stream);
  hist_kernel<<<EB, 256, 0, stream>>>(dst, cursor, N_EDGES);
  scan_kernel<<<1, 1024, 0, stream>>>(cursor, rowptr, N_NODES);
  hipMemsetAsync(cursor, 0, N_NODES * sizeof(int), stream);
  bucket_kernel<<<EB, 256, 0, stream>>>(src, dst, eattr, rowptr, cursor, esrc, eww, N_EDGES);

  // ---- graph segment pointers ----
  hipMemsetAsync(gcnt, 0, N_GRAPH * sizeof(int), stream);
  hist_kernel<<<NB, 256, 0, stream>>>(batch, gcnt, N_NODES);
  scan_kernel<<<1, 1024, 0, stream>>>(gcnt, gptr, N_GRAPH);

  const int aggBlocks = (N_NODES * 64 + 255) / 256;

  // ---- layer 1: D_in=128 -> 128 ----
  agg_kernel<128><<<aggBlocks, 256, 0, stream>>>(x, rowptr, esrc, eww, bufC);
  {
    dim3 grid((N_NODES + 63) / 64, 128 / 64);
    gemm_dual_kernel<<<grid, 256, 0, stream>>>(bufC, x, w_rel1, w_root1, b_rel1, bufA,
                                               N_NODES, 128, 128);
  }
  hipMemsetAsync(sums, 0, 2 * 128 * sizeof(float), stream);
  bn_stats_kernel<<<dim3(1, 128), 128, 0, stream>>>(bufA, sums, N_NODES, 128);
  bn_apply_kernel<<<(N_NODES * 128 + 255) / 256, 256, 0, stream>>>(bufA, sums, gamma1, beta1,
                                                                   N_NODES, 128);
  pool_kernel<<<N_GRAPH, 128, 0, stream>>>(bufA, gptr, zbuf, 128, 0);

  // ---- layer 2: 128 -> 256 ----
  agg_kernel<128><<<aggBlocks, 256, 0, stream>>>(bufA, rowptr, esrc, eww, bufC);
  {
    dim3 grid((N_NODES + 63) / 64, 256 / 64);
    gemm_dual_kernel<<<grid, 256, 0, stream>>>(bufC, bufA, w_rel2, w_root2, b_rel2, bufB,
                                               N_NODES, 128, 256);
  }
  hipMemsetAsync(sums, 0, 2 * 256 * sizeof(float), stream);
  bn_stats_kernel<<<dim3(2, 128), 128, 0, stream>>>(bufB, sums, N_NODES, 256);
  bn_apply_kernel<<<(N_NODES * 256 + 255) / 256, 256, 0, stream>>>(bufB, sums, gamma2, beta2,
                                                                   N_NODES, 256);
  pool_kernel<<<N_GRAPH, 128, 0, stream>>>(bufB, gptr, zbuf, 256, 384);

  // ---- layer 3: 256 -> 384 ----
  agg_kernel<256><<<aggBlocks, 256, 0, stream>>>(bufB, rowptr, esrc, eww, bufC);
  {
    dim3 grid((N_NODES + 63) / 64, 384 / 64);
    gemm_dual_kernel<<<grid, 256, 0, stream>>>(bufC, bufB, w_rel3, w_root3, b_rel3, bufA,
                                               N_NODES, 256, 384);
  }
  hipMemsetAsync(sums, 0, 2 * 384 * sizeof(float), stream);
  bn_stats_kernel<<<dim3(3, 128), 128, 0, stream>>>(bufA, sums, N_NODES, 384);
  bn_apply_kernel<<<(N_NODES * 384 + 255) / 256, 256, 0, stream>>>(bufA, sums, gamma3, beta3,
                                                                   N_NODES, 384);
  pool_kernel<<<N_GRAPH, 128, 0, stream>>>(bufA, gptr, zbuf, 384, 1152);

  // ---- FC head ----
  fc_kernel<<<N_GRAPH, 128, 0, stream>>>(zbuf, w_lin1, b_lin1, w_lin2, b_lin2, w_lin3, b_lin3,
                                         outp);
}

// Round 2
// 1352.418 us; speedup vs baseline: 1.4912x; 1.4912x over previous
//
#include <hip/hip_runtime.h>
#include <cstdint>
#include <cstddef>

#define N_NODES 50000
#define M_PAD   50048   // 391 * 128
#define N_EDGES 800000
#define N_GRAPH 256
#define Z_DIM   2304

static constexpr float LEAKY  = 0.01f;
static constexpr float BN_EPS = 1e-5f;

typedef short short8 __attribute__((ext_vector_type(8)));
typedef float floatx4 __attribute__((ext_vector_type(4)));

__device__ __forceinline__ unsigned short f2b(float f) {
  union { float f; unsigned int u; } v; v.f = f;
  unsigned int u = v.u;
  unsigned int r = (u + 0x7FFFu + ((u >> 16) & 1u)) >> 16;
  return (unsigned short)r;
}
__device__ __forceinline__ float b2f(unsigned short h) {
  union { unsigned int u; float f; } v; v.u = ((unsigned int)h) << 16;
  return v.f;
}

// ---------------- CSR build ----------------

__global__ void hist_kernel(const int* __restrict__ idx, int* __restrict__ cnt, int n) {
  int i = blockIdx.x * blockDim.x + threadIdx.x;
  if (i < n) atomicAdd(&cnt[idx[i]], 1);
}

__global__ __launch_bounds__(1024) void scan_kernel(const int* __restrict__ in,
                                                    int* __restrict__ out, int n) {
  __shared__ int smem[1024];
  __shared__ int carry_s;
  if (threadIdx.x == 0) carry_s = 0;
  __syncthreads();
  for (int base = 0; base < n; base += 1024) {
    int i = base + (int)threadIdx.x;
    int v = (i < n) ? in[i] : 0;
    smem[threadIdx.x] = v;
    __syncthreads();
    for (int off = 1; off < 1024; off <<= 1) {
      int t = (threadIdx.x >= (unsigned)off) ? smem[threadIdx.x - off] : 0;
      __syncthreads();
      smem[threadIdx.x] += t;
      __syncthreads();
    }
    if (i < n) out[i] = carry_s + smem[threadIdx.x] - v;
    __syncthreads();
    if (threadIdx.x == 1023) carry_s += smem[1023];
    __syncthreads();
  }
  if (threadIdx.x == 0) out[n] = carry_s;
}

__global__ void bucket_kernel(const int* __restrict__ src, const int* __restrict__ dst,
                              const float* __restrict__ ew, const int* __restrict__ rowptr,
                              int* __restrict__ cursor, int* __restrict__ esrc,
                              float* __restrict__ eww, int E) {
  int e = blockIdx.x * blockDim.x + threadIdx.x;
  if (e < E) {
    int d = dst[e];
    int p = rowptr[d] + atomicAdd(&cursor[d], 1);
    esrc[p] = src[e];
    eww[p]  = ew[e];
  }
}

// ---------------- prep: casts & weight transpose ----------------

// cast fp32 -> bf16 (pairwise)
__global__ void cast_bf16_kernel(const float* __restrict__ in,
                                 unsigned short* __restrict__ out, int npair) {
  int i = blockIdx.x * blockDim.x + threadIdx.x;
  if (i >= npair) return;
  float2 v = *(const float2*)(in + 2 * (size_t)i);
  ((unsigned int*)out)[i] = (unsigned int)f2b(v.x) | ((unsigned int)f2b(v.y) << 16);
}

// Wt[n][k'] bf16, k' in [0,2K): k'<K -> w_rel[k'][n], else w_root[k'-K][n]
__global__ void wt_build_kernel(const float* __restrict__ wrel, const float* __restrict__ wroot,
                                unsigned short* __restrict__ wt, int K, int N) {
  int n = blockIdx.x;
  int K2 = 2 * K;
  for (int k = threadIdx.x; k < K2; k += blockDim.x) {
    float v = (k < K) ? wrel[(size_t)k * N + n] : wroot[(size_t)(k - K) * N + n];
    wt[(size_t)n * K2 + k] = f2b(v);
  }
}

// ---------------- aggregation: one wave per dst node, bf16 in/out ----------------

template <int D>  // feature dim, multiple of 128
__global__ void agg_bf16_kernel(const unsigned short* __restrict__ h,
                                const int* __restrict__ rowptr,
                                const int* __restrict__ esrc, const float* __restrict__ eww,
                                unsigned short* __restrict__ agg) {
  int gid  = blockIdx.x * blockDim.x + threadIdx.x;
  int node = gid >> 6;
  int lane = threadIdx.x & 63;
  if (node >= N_NODES) return;
  int beg = rowptr[node], end = rowptr[node + 1];
  constexpr int NP = D / 128;  // uint (2 bf16) per lane
  float acc0[NP], acc1[NP];
#pragma unroll
  for (int i = 0; i < NP; ++i) { acc0[i] = 0.f; acc1[i] = 0.f; }
  for (int p = beg; p < end; ++p) {
    int   s = esrc[p];
    float w = eww[p];
    const unsigned int* row = (const unsigned int*)(h + (size_t)s * D);
#pragma unroll
    for (int i = 0; i < NP; ++i) {
      unsigned int u = row[lane + 64 * i];
      acc0[i] += b2f((unsigned short)(u & 0xFFFF)) * w;
      acc1[i] += b2f((unsigned short)(u >> 16)) * w;
    }
  }
  unsigned int* o = (unsigned int*)(agg + (size_t)node * D);
#pragma unroll
  for (int i = 0; i < NP; ++i)
    o[lane + 64 * i] = (unsigned int)f2b(acc0[i]) | ((unsigned int)f2b(acc1[i]) << 16);
}

// ---------------- MFMA GEMM: out = [Aagg|Ah] @ Wt' + bias, leaky ----------------
// Aagg/Ah: [M_PAD][K] bf16 row-major. Wt: [N][2K] bf16 (pre-transposed).
// out: [M][N] fp32. 128x128 tile, BK=32, 4 waves x 4x4 mfma 16x16x32.

__global__ __launch_bounds__(256) void gemm_mfma_kernel(
    const unsigned short* __restrict__ Aagg, const unsigned short* __restrict__ Ah,
    const unsigned short* __restrict__ Wt, const float* __restrict__ bias,
    float* __restrict__ out, int M, int K, int N) {
  constexpr int LDA = 40;  // bf16 elems per LDS row (32 + 8 pad -> 2-way aliasing only)
  __shared__ unsigned short As[128 * LDA];
  __shared__ unsigned short Bs[128 * LDA];

  const int m0 = blockIdx.x * 128;
  const int n0 = blockIdx.y * 128;
  const int t  = threadIdx.x;
  const int lane = t & 63;
  const int w    = t >> 6;
  const int wm   = (w & 1) * 64;
  const int wn   = (w >> 1) * 64;
  const int l16  = lane & 15;
  const int lq   = lane >> 4;
  const int K2   = 2 * K;

  floatx4 acc[4][4];
#pragma unroll
  for (int i = 0; i < 4; ++i)
#pragma unroll
    for (int j = 0; j < 4; ++j) acc[i][j] = (floatx4){0.f, 0.f, 0.f, 0.f};

  // staging: 512 chunks of 8 bf16 per tile; thread t does chunks t and t+256
  const int r0 = t >> 2;                 // chunk row 0..63
  const int c80 = (t & 3) * 8;           // chunk col offset
  // chunk t+256: row = (t+256)>>2 = r0+64, same c8

  for (int k0 = 0; k0 < K2; k0 += 32) {
    const unsigned short* Asrc;
    int kbase;
    if (k0 < K) { Asrc = Aagg; kbase = k0; } else { Asrc = Ah; kbase = k0 - K; }

    short8 a0 = *(const short8*)(Asrc + (size_t)(m0 + r0) * K + kbase + c80);
    short8 a1 = *(const short8*)(Asrc + (size_t)(m0 + r0 + 64) * K + kbase + c80);
    short8 b0 = *(const short8*)(Wt + (size_t)(n0 + r0) * K2 + k0 + c80);
    short8 b1 = *(const short8*)(Wt + (size_t)(n0 + r0 + 64) * K2 + k0 + c80);

    __syncthreads();
    *(short8*)(As + r0 * LDA + c80)        = a0;
    *(short8*)(As + (r0 + 64) * LDA + c80) = a1;
    *(short8*)(Bs + r0 * LDA + c80)        = b0;
    *(short8*)(Bs + (r0 + 64) * LDA + c80) = b1;
    __syncthreads();

    short8 af[4], bfr[4];
#pragma unroll
    for (int i = 0; i < 4; ++i)
      af[i] = *(const short8*)(As + (wm + i * 16 + l16) * LDA + lq * 8);
#pragma unroll
    for (int j = 0; j < 4; ++j)
      bfr[j] = *(const short8*)(Bs + (wn + j * 16 + l16) * LDA + lq * 8);

#pragma unroll
    for (int i = 0; i < 4; ++i)
#pragma unroll
      for (int j = 0; j < 4; ++j)
        acc[i][j] = __builtin_amdgcn_mfma_f32_16x16x32_bf16(af[i], bfr[j], acc[i][j], 0, 0, 0);
  }

#pragma unroll
  for (int i = 0; i < 4; ++i) {
    const int mbase = m0 + wm + i * 16 + lq * 4;
#pragma unroll
    for (int j = 0; j < 4; ++j) {
      const int n = n0 + wn + j * 16 + l16;
      const float bb = bias[n];
#pragma unroll
      for (int r = 0; r < 4; ++r) {
        const int m = mbase + r;
        if (m < M) {
          float v = acc[i][j][r] + bb;
          out[(size_t)m * N + n] = v > 0.f ? v : LEAKY * v;
        }
      }
    }
  }
}

// ---------------- BatchNorm ----------------

__global__ __launch_bounds__(128) void bn_stats_kernel(const float* __restrict__ h,
                                                       float* __restrict__ sums,
                                                       int n, int C) {
  const int c = blockIdx.x * 128 + threadIdx.x;
  const int nb = gridDim.y;
  const int rows_per = (n + nb - 1) / nb;
  const int r0 = blockIdx.y * rows_per;
  const int r1 = min(n, r0 + rows_per);
  float s = 0.f, ss = 0.f;
  for (int r = r0; r < r1; ++r) {
    const float v = h[(size_t)r * C + c];
    s += v;
    ss += v * v;
  }
  atomicAdd(&sums[c], s);
  atomicAdd(&sums[C + c], ss);
}

// sums[2C+c] = scale, sums[3C+c] = shift
__global__ void bn_finalize_kernel(float* __restrict__ sums, const float* __restrict__ gamma,
                                   const float* __restrict__ beta, int n, int C) {
  int c = blockIdx.x * blockDim.x + threadIdx.x;
  if (c >= C) return;
  const float inv_n = 1.f / (float)n;
  const float mu  = sums[c] * inv_n;
  const float var = sums[C + c] * inv_n - mu * mu;
  const float sc  = rsqrtf(var + BN_EPS) * gamma[c];
  sums[2 * C + c] = sc;
  sums[3 * C + c] = beta[c] - mu * sc;
}

// apply BN, write bf16
__global__ void bn_apply_bf16_kernel(const float* __restrict__ hpre, const float* __restrict__ sums,
                                     unsigned short* __restrict__ H, int n, int C) {
  int i = blockIdx.x * blockDim.x + threadIdx.x;  // pair index
  int total = n * C / 2;
  if (i >= total) return;
  int c0 = (2 * i) % C;
  float2 v = *(const float2*)(hpre + 2 * (size_t)i);
  const float y0 = v.x * sums[2 * C + c0] + sums[3 * C + c0];
  const float y1 = v.y * sums[2 * C + c0 + 1] + sums[3 * C + c0 + 1];
  ((unsigned int*)H)[i] = (unsigned int)f2b(y0) | ((unsigned int)f2b(y1) << 16);
}

// ---------------- pooling (max | mean | sum) per graph, bf16 input ----------------

__global__ __launch_bounds__(128) void pool_kernel(const unsigned short* __restrict__ h,
                                                   const int* __restrict__ gptr,
                                                   float* __restrict__ z, int C, int zoff) {
  const int g = blockIdx.x;
  const int beg = gptr[g], end = gptr[g + 1];
  const int cnt = end - beg;
  for (int c = threadIdx.x; c < C; c += 128) {
    float mx = -3.4e38f, s = 0.f;
    for (int r = beg; r < end; ++r) {
      const float v = b2f(h[(size_t)r * C + c]);
      mx = fmaxf(mx, v);
      s += v;
    }
    const float mean = s / (float)(cnt > 0 ? cnt : 1);
    if (cnt == 0) mx = 0.f;
    float* zg = z + (size_t)g * Z_DIM + zoff;
    zg[c]         = mx;
    zg[C + c]     = mean;
    zg[2 * C + c] = s;
  }
}

// ---------------- FC head ----------------

__global__ __launch_bounds__(128) void fc_kernel(const float* __restrict__ z,
                                                 const float* __restrict__ w1, const float* __restrict__ b1,
                                                 const float* __restrict__ w2, const float* __restrict__ b2,
                                                 const float* __restrict__ w3, const float* __restrict__ b3,
                                                 float* __restrict__ out) {
  __shared__ float zs[Z_DIM];
  __shared__ float h1[128];
  __shared__ float red[128][2];
  __shared__ float y2[2];
  const int g = blockIdx.x;
  const int t = threadIdx.x;
  for (int i = t; i < Z_DIM; i += 128) zs[i] = z[(size_t)g * Z_DIM + i];
  __syncthreads();

  float acc = b1[t];
  for (int k = 0; k < Z_DIM; ++k) acc += zs[k] * w1[(size_t)k * 128 + t];
  h1[t] = fmaxf(acc, 0.f);
  __syncthreads();

  red[t][0] = h1[t] * w2[t * 2 + 0];
  red[t][1] = h1[t] * w2[t * 2 + 1];
  __syncthreads();
  if (t < 2) {
    float s = b2[t];
    for (int k = 0; k < 128; ++k) s += red[k][t];
    y2[t] = fmaxf(s, 0.f);
  }
  __syncthreads();
  if (t == 0) {
    const float z0 = y2[0] * w3[0] + y2[1] * w3[2] + b3[0];
    const float z1 = y2[0] * w3[1] + y2[1] * w3[3] + b3[1];
    const float m  = fmaxf(z0, z1);
    const float lse = m + logf(expf(z0 - m) + expf(z1 - m));
    out[g * 2 + 0] = z0 - lse;
    out[g * 2 + 1] = z1 - lse;
  }
}

// ---------------- launch ----------------

extern "C" void kernel_launch(void* const* d_in, const int* in_sizes, int n_in,
                              void* d_out, int out_size, void* d_ws, size_t ws_size,
                              hipStream_t stream) {
  (void)in_sizes; (void)n_in; (void)out_size; (void)ws_size;
  const float* x        = (const float*)d_in[0];
  const int*   eidx     = (const int*)d_in[1];
  const int*   batch    = (const int*)d_in[2];
  const float* eattr    = (const float*)d_in[3];
  const float* w_rel1   = (const float*)d_in[4];
  const float* b_rel1   = (const float*)d_in[5];
  const float* w_root1  = (const float*)d_in[6];
  const float* w_rel2   = (const float*)d_in[7];
  const float* b_rel2   = (const float*)d_in[8];
  const float* w_root2  = (const float*)d_in[9];
  const float* w_rel3   = (const float*)d_in[10];
  const float* b_rel3   = (const float*)d_in[11];
  const float* w_root3  = (const float*)d_in[12];
  const float* gamma1   = (const float*)d_in[13];
  const float* beta1    = (const float*)d_in[14];
  const float* gamma2   = (const float*)d_in[15];
  const float* beta2    = (const float*)d_in[16];
  const float* gamma3   = (const float*)d_in[17];
  const float* beta3    = (const float*)d_in[18];
  const float* w_lin1   = (const float*)d_in[19];
  const float* b_lin1   = (const float*)d_in[20];
  const float* w_lin2   = (const float*)d_in[21];
  const float* b_lin2   = (const float*)d_in[22];
  const float* w_lin3   = (const float*)d_in[23];
  const float* b_lin3   = (const float*)d_in[24];

  const int* src = eidx;
  const int* dst = eidx + N_EDGES;
  float* outp = (float*)d_out;

  char* ws = (char*)d_ws;
  size_t off = 0;
  auto alloc = [&](size_t bytes) -> void* {
    void* p = ws + off;
    off += (bytes + 255) & ~(size_t)255;
    return p;
  };
  int*   rowptr = (int*)alloc((N_NODES + 1) * sizeof(int));
  int*   cursor = (int*)alloc(N_NODES * sizeof(int));
  int*   gptr   = (int*)alloc((N_GRAPH + 1) * sizeof(int));
  int*   gcnt   = (int*)alloc(N_GRAPH * sizeof(int));
  int*   esrc   = (int*)alloc(N_EDGES * sizeof(int));
  float* eww    = (float*)alloc(N_EDGES * sizeof(float));
  float* sums   = (float*)alloc(4 * 384 * sizeof(float));
  float* zbuf   = (float*)alloc((size_t)N_GRAPH * Z_DIM * sizeof(float));
  unsigned short* xb   = (unsigned short*)alloc((size_t)M_PAD * 128 * 2);
  unsigned short* H1   = (unsigned short*)alloc((size_t)M_PAD * 128 * 2);
  unsigned short* H2   = (unsigned short*)alloc((size_t)M_PAD * 256 * 2);
  unsigned short* H3   = (unsigned short*)alloc((size_t)M_PAD * 384 * 2);
  unsigned short* aggb = (unsigned short*)alloc((size_t)M_PAD * 256 * 2);
  float* hpre = (float*)alloc((size_t)N_NODES * 384 * sizeof(float));
  unsigned short* wt1 = (unsigned short*)alloc((size_t)128 * 256 * 2);
  unsigned short* wt2 = (unsigned short*)alloc((size_t)256 * 256 * 2);
  unsigned short* wt3 = (unsigned short*)alloc((size_t)384 * 512 * 2);

  const int EB = (N_EDGES + 255) / 256;
  const int NB = (N_NODES + 255) / 256;

  // ---- CSR by dst ----
  hipMemsetAsync(cursor, 0, N_NODES * sizeof(int), stream);
  hist_kernel<<<EB, 256, 0, stream>>>(dst, cursor, N_EDGES);
  scan_kernel<<<1, 1024, 0, stream>>>(cursor, rowptr, N_NODES);
  hipMemsetAsync(cursor, 0, N_NODES * sizeof(int), stream);
  bucket_kernel<<<EB, 256, 0, stream>>>(src, dst, eattr, rowptr, cursor, esrc, eww, N_EDGES);

  // ---- graph segment pointers ----
  hipMemsetAsync(gcnt, 0, N_GRAPH * sizeof(int), stream);
  hist_kernel<<<NB, 256, 0, stream>>>(batch, gcnt, N_NODES);
  scan_kernel<<<1, 1024, 0, stream>>>(gcnt, gptr, N_GRAPH);

  // ---- prep: casts + weight transposes ----
  cast_bf16_kernel<<<(N_NODES * 128 / 2 + 255) / 256, 256, 0, stream>>>(x, xb, N_NODES * 128 / 2);
  wt_build_kernel<<<128, 256, 0, stream>>>(w_rel1, w_root1, wt1, 128, 128);
  wt_build_kernel<<<256, 256, 0, stream>>>(w_rel2, w_root2, wt2, 128, 256);
  wt_build_kernel<<<384, 256, 0, stream>>>(w_rel3, w_root3, wt3, 256, 384);

  const int aggBlocks = (N_NODES * 64 + 255) / 256;
  const int MB = M_PAD / 128;  // 391

  // ---- layer 1: 128 -> 128 ----
  agg_bf16_kernel<128><<<aggBlocks, 256, 0, stream>>>(xb, rowptr, esrc, eww, aggb);
  gemm_mfma_kernel<<<dim3(MB, 1), 256, 0, stream>>>(aggb, xb, wt1, b_rel1, hpre,
                                                    N_NODES, 128, 128);
  hipMemsetAsync(sums, 0, 4 * 128 * sizeof(float), stream);
  bn_stats_kernel<<<dim3(1, 256), 128, 0, stream>>>(hpre, sums, N_NODES, 128);
  bn_finalize_kernel<<<1, 128, 0, stream>>>(sums, gamma1, beta1, N_NODES, 128);
  bn_apply_bf16_kernel<<<(N_NODES * 128 / 2 + 255) / 256, 256, 0, stream>>>(hpre, sums, H1,
                                                                            N_NODES, 128);
  pool_kernel<<<N_GRAPH, 128, 0, stream>>>(H1, gptr, zbuf, 128, 0);

  // ---- layer 2: 128 -> 256 ----
  agg_bf16_kernel<128><<<aggBlocks, 256, 0, stream>>>(H1, rowptr, esrc, eww, aggb);
  gemm_mfma_kernel<<<dim3(MB, 2), 256, 0, stream>>>(aggb, H1, wt2, b_rel2, hpre,
                                                    N_NODES, 128, 256);
  hipMemsetAsync(sums, 0, 4 * 256 * sizeof(float), stream);
  bn_stats_kernel<<<dim3(2, 256), 128, 0, stream>>>(hpre, sums, N_NODES, 256);
  bn_finalize_kernel<<<1, 256, 0, stream>>>(sums, gamma2, beta2, N_NODES, 256);
  bn_apply_bf16_kernel<<<(N_NODES * 256 / 2 + 255) / 256, 256, 0, stream>>>(hpre, sums, H2,
                                                                            N_NODES, 256);
  pool_kernel<<<N_GRAPH, 128, 0, stream>>>(H2, gptr, zbuf, 256, 384);

  // ---- layer 3: 256 -> 384 ----
  agg_bf16_kernel<256><<<aggBlocks, 256, 0, stream>>>(H2, rowptr, esrc, eww, aggb);
  gemm_mfma_kernel<<<dim3(MB, 3), 256, 0, stream>>>(aggb, H2, wt3, b_rel3, hpre,
                                                    N_NODES, 256, 384);
  hipMemsetAsync(sums, 0, 4 * 384 * sizeof(float), stream);
  bn_stats_kernel<<<dim3(3, 256), 128, 0, stream>>>(hpre, sums, N_NODES, 384);
  bn_finalize_kernel<<<2, 256, 0, stream>>>(sums, gamma3, beta3, N_NODES, 384);
  bn_apply_bf16_kernel<<<(N_NODES * 384 / 2 + 255) / 256, 256, 0, stream>>>(hpre, sums, H3,
                                                                            N_NODES, 384);
  pool_kernel<<<N_GRAPH, 128, 0, stream>>>(H3, gptr, zbuf, 384, 1152);

  // ---- FC head ----
  fc_kernel<<<N_GRAPH, 128, 0, stream>>>(zbuf, w_lin1, b_lin1, w_lin2, b_lin2, w_lin3, b_lin3,
                                         outp);
}

// Round 3
// 1055.186 us; speedup vs baseline: 1.9112x; 1.2817x over previous
//
#include <hip/hip_runtime.h>
#include <cstdint>
#include <cstddef>

#define N_NODES 50000
#define M_PAD   50048   // 391 * 128
#define N_EDGES 800000
#define N_GRAPH 256
#define Z_DIM   2304

static constexpr float LEAKY  = 0.01f;
static constexpr float BN_EPS = 1e-5f;

typedef short short8 __attribute__((ext_vector_type(8)));
typedef float floatx4 __attribute__((ext_vector_type(4)));

__device__ __forceinline__ unsigned short f2b(float f) {
  union { float f; unsigned int u; } v; v.f = f;
  unsigned int u = v.u;
  unsigned int r = (u + 0x7FFFu + ((u >> 16) & 1u)) >> 16;
  return (unsigned short)r;
}
__device__ __forceinline__ float b2f(unsigned short h) {
  union { unsigned int u; float f; } v; v.u = ((unsigned int)h) << 16;
  return v.f;
}

// ---------------- CSR build ----------------

__global__ void hist_kernel(const int* __restrict__ idx, int* __restrict__ cnt, int n) {
  int i = blockIdx.x * blockDim.x + threadIdx.x;
  if (i < n) atomicAdd(&cnt[idx[i]], 1);
}

__global__ __launch_bounds__(1024) void scan_kernel(const int* __restrict__ in,
                                                    int* __restrict__ out, int n) {
  __shared__ int smem[1024];
  __shared__ int carry_s;
  if (threadIdx.x == 0) carry_s = 0;
  __syncthreads();
  for (int base = 0; base < n; base += 1024) {
    int i = base + (int)threadIdx.x;
    int v = (i < n) ? in[i] : 0;
    smem[threadIdx.x] = v;
    __syncthreads();
    for (int off = 1; off < 1024; off <<= 1) {
      int t = (threadIdx.x >= (unsigned)off) ? smem[threadIdx.x - off] : 0;
      __syncthreads();
      smem[threadIdx.x] += t;
      __syncthreads();
    }
    if (i < n) out[i] = carry_s + smem[threadIdx.x] - v;
    __syncthreads();
    if (threadIdx.x == 1023) carry_s += smem[1023];
    __syncthreads();
  }
  if (threadIdx.x == 0) out[n] = carry_s;
}

__global__ void bucket_kernel(const int* __restrict__ src, const int* __restrict__ dst,
                              const float* __restrict__ ew, const int* __restrict__ rowptr,
                              int* __restrict__ cursor, int* __restrict__ esrc,
                              float* __restrict__ eww, int E) {
  int e = blockIdx.x * blockDim.x + threadIdx.x;
  if (e < E) {
    int d = dst[e];
    int p = rowptr[d] + atomicAdd(&cursor[d], 1);
    esrc[p] = src[e];
    eww[p]  = ew[e];
  }
}

// ---------------- prep: casts & weight transpose ----------------

__global__ void cast_bf16_kernel(const float* __restrict__ in,
                                 unsigned short* __restrict__ out, int npair) {
  int i = blockIdx.x * blockDim.x + threadIdx.x;
  if (i >= npair) return;
  float2 v = *(const float2*)(in + 2 * (size_t)i);
  ((unsigned int*)out)[i] = (unsigned int)f2b(v.x) | ((unsigned int)f2b(v.y) << 16);
}

__global__ void wt_build_kernel(const float* __restrict__ wrel, const float* __restrict__ wroot,
                                unsigned short* __restrict__ wt, int K, int N) {
  int n = blockIdx.x;
  int K2 = 2 * K;
  for (int k = threadIdx.x; k < K2; k += blockDim.x) {
    float v = (k < K) ? wrel[(size_t)k * N + n] : wroot[(size_t)(k - K) * N + n];
    wt[(size_t)n * K2 + k] = f2b(v);
  }
}

// ---------------- aggregation: one wave per dst node, bf16 in/out ----------------

template <int D>
__global__ void agg_bf16_kernel(const unsigned short* __restrict__ h,
                                const int* __restrict__ rowptr,
                                const int* __restrict__ esrc, const float* __restrict__ eww,
                                unsigned short* __restrict__ agg) {
  int gid  = blockIdx.x * blockDim.x + threadIdx.x;
  int node = gid >> 6;
  int lane = threadIdx.x & 63;
  if (node >= N_NODES) return;
  int beg = rowptr[node], end = rowptr[node + 1];
  constexpr int NP = D / 128;
  float acc0[NP], acc1[NP];
#pragma unroll
  for (int i = 0; i < NP; ++i) { acc0[i] = 0.f; acc1[i] = 0.f; }
  for (int p = beg; p < end; ++p) {
    int   s = esrc[p];
    float w = eww[p];
    const unsigned int* row = (const unsigned int*)(h + (size_t)s * D);
#pragma unroll
    for (int i = 0; i < NP; ++i) {
      unsigned int u = row[lane + 64 * i];
      acc0[i] += b2f((unsigned short)(u & 0xFFFF)) * w;
      acc1[i] += b2f((unsigned short)(u >> 16)) * w;
    }
  }
  unsigned int* o = (unsigned int*)(agg + (size_t)node * D);
#pragma unroll
  for (int i = 0; i < NP; ++i)
    o[lane + 64 * i] = (unsigned int)f2b(acc0[i]) | ((unsigned int)f2b(acc1[i]) << 16);
}

// ---------------- MFMA GEMM ----------------

__global__ __launch_bounds__(256) void gemm_mfma_kernel(
    const unsigned short* __restrict__ Aagg, const unsigned short* __restrict__ Ah,
    const unsigned short* __restrict__ Wt, const float* __restrict__ bias,
    float* __restrict__ out, int M, int K, int N) {
  constexpr int LDA = 40;
  __shared__ unsigned short As[128 * LDA];
  __shared__ unsigned short Bs[128 * LDA];

  const int m0 = blockIdx.x * 128;
  const int n0 = blockIdx.y * 128;
  const int t  = threadIdx.x;
  const int lane = t & 63;
  const int w    = t >> 6;
  const int wm   = (w & 1) * 64;
  const int wn   = (w >> 1) * 64;
  const int l16  = lane & 15;
  const int lq   = lane >> 4;
  const int K2   = 2 * K;

  floatx4 acc[4][4];
#pragma unroll
  for (int i = 0; i < 4; ++i)
#pragma unroll
    for (int j = 0; j < 4; ++j) acc[i][j] = (floatx4){0.f, 0.f, 0.f, 0.f};

  const int r0 = t >> 2;
  const int c80 = (t & 3) * 8;

  for (int k0 = 0; k0 < K2; k0 += 32) {
    const unsigned short* Asrc;
    int kbase;
    if (k0 < K) { Asrc = Aagg; kbase = k0; } else { Asrc = Ah; kbase = k0 - K; }

    short8 a0 = *(const short8*)(Asrc + (size_t)(m0 + r0) * K + kbase + c80);
    short8 a1 = *(const short8*)(Asrc + (size_t)(m0 + r0 + 64) * K + kbase + c80);
    short8 b0 = *(const short8*)(Wt + (size_t)(n0 + r0) * K2 + k0 + c80);
    short8 b1 = *(const short8*)(Wt + (size_t)(n0 + r0 + 64) * K2 + k0 + c80);

    __syncthreads();
    *(short8*)(As + r0 * LDA + c80)        = a0;
    *(short8*)(As + (r0 + 64) * LDA + c80) = a1;
    *(short8*)(Bs + r0 * LDA + c80)        = b0;
    *(short8*)(Bs + (r0 + 64) * LDA + c80) = b1;
    __syncthreads();

    short8 af[4], bfr[4];
#pragma unroll
    for (int i = 0; i < 4; ++i)
      af[i] = *(const short8*)(As + (wm + i * 16 + l16) * LDA + lq * 8);
#pragma unroll
    for (int j = 0; j < 4; ++j)
      bfr[j] = *(const short8*)(Bs + (wn + j * 16 + l16) * LDA + lq * 8);

#pragma unroll
    for (int i = 0; i < 4; ++i)
#pragma unroll
      for (int j = 0; j < 4; ++j)
        acc[i][j] = __builtin_amdgcn_mfma_f32_16x16x32_bf16(af[i], bfr[j], acc[i][j], 0, 0, 0);
  }

#pragma unroll
  for (int i = 0; i < 4; ++i) {
    const int mbase = m0 + wm + i * 16 + lq * 4;
#pragma unroll
    for (int j = 0; j < 4; ++j) {
      const int n = n0 + wn + j * 16 + l16;
      const float bb = bias[n];
#pragma unroll
      for (int r = 0; r < 4; ++r) {
        const int m = mbase + r;
        if (m < M) {
          float v = acc[i][j][r] + bb;
          out[(size_t)m * N + n] = v > 0.f ? v : LEAKY * v;
        }
      }
    }
  }
}

// ---------------- BatchNorm stats ----------------

__global__ __launch_bounds__(128) void bn_stats_kernel(const float* __restrict__ h,
                                                       float* __restrict__ sums,
                                                       int n, int C) {
  const int c = blockIdx.x * 128 + threadIdx.x;
  const int nb = gridDim.y;
  const int rows_per = (n + nb - 1) / nb;
  const int r0 = blockIdx.y * rows_per;
  const int r1 = min(n, r0 + rows_per);
  float s = 0.f, ss = 0.f;
  for (int r = r0; r < r1; ++r) {
    const float v = h[(size_t)r * C + c];
    s += v;
    ss += v * v;
  }
  atomicAdd(&sums[c], s);
  atomicAdd(&sums[C + c], ss);
}

__global__ void bn_finalize_kernel(float* __restrict__ sums, const float* __restrict__ gamma,
                                   const float* __restrict__ beta, int n, int C) {
  int c = blockIdx.x * blockDim.x + threadIdx.x;
  if (c >= C) return;
  const float inv_n = 1.f / (float)n;
  const float mu  = sums[c] * inv_n;
  const float var = sums[C + c] * inv_n - mu * mu;
  const float sc  = rsqrtf(var + BN_EPS) * gamma[c];
  sums[2 * C + c] = sc;
  sums[3 * C + c] = beta[c] - mu * sc;
}

// ---------------- fused BN-apply + pooling ----------------
// Grid: (ceil(n/64), C/128), 128 threads. Thread = one channel, 64 rows.
// z layout per graph: [zoff..zoff+C) = max (as ordered uint keys during accum),
// [zoff+C..zoff+2C) = mean (finalize), [zoff+2C..zoff+3C) = sum.

__device__ __forceinline__ void pool_flush(float* __restrict__ z, int g, int C, int zoff,
                                           int c, float mx, float s) {
  float* zg = z + (size_t)g * Z_DIM + zoff;
  unsigned key = __float_as_uint(mx);
  key ^= (key & 0x80000000u) ? 0xFFFFFFFFu : 0x80000000u;
  atomicMax((unsigned int*)(zg + c), key);
  atomicAdd(zg + 2 * C + c, s);
}

__global__ __launch_bounds__(128) void bn_apply_pool_kernel(
    const float* __restrict__ hpre, const float* __restrict__ sums,
    unsigned short* __restrict__ H, const int* __restrict__ batch,
    float* __restrict__ z, int n, int C, int zoff) {
  __shared__ int bs[64];
  const int c  = blockIdx.y * 128 + threadIdx.x;
  const int r0 = blockIdx.x * 64;
  const int r1 = min(n, r0 + 64);
  if (threadIdx.x < 64 && r0 + (int)threadIdx.x < n) bs[threadIdx.x] = batch[r0 + threadIdx.x];
  __syncthreads();
  const float sc = sums[2 * C + c];
  const float sh = sums[3 * C + c];
  int   cur_g = bs[0];
  float mx = -3.4e38f, s = 0.f;
  for (int r = r0; r < r1; ++r) {
    const int g = bs[r - r0];
    if (g != cur_g) {
      pool_flush(z, cur_g, C, zoff, c, mx, s);
      mx = -3.4e38f; s = 0.f; cur_g = g;
    }
    const float v = hpre[(size_t)r * C + c] * sc + sh;
    H[(size_t)r * C + c] = f2b(v);
    mx = fmaxf(mx, v);
    s += v;
  }
  pool_flush(z, cur_g, C, zoff, c, mx, s);
}

__global__ void pool_finalize_kernel(float* __restrict__ z, const int* __restrict__ gptr,
                                     int C, int zoff) {
  int i = blockIdx.x * blockDim.x + threadIdx.x;
  if (i >= N_GRAPH * C) return;
  int g = i / C, c = i % C;
  int cnt = gptr[g + 1] - gptr[g];
  float* zg = z + (size_t)g * Z_DIM + zoff;
  unsigned key = __float_as_uint(zg[c]);
  key ^= (key & 0x80000000u) ? 0x80000000u : 0xFFFFFFFFu;
  float mx = __uint_as_float(key);
  float sum = zg[2 * C + c];
  zg[c]     = (cnt > 0) ? mx : 0.f;
  zg[C + c] = sum / (float)(cnt > 0 ? cnt : 1);
}

// ---------------- FC head ----------------

__global__ __launch_bounds__(128) void fc_kernel(const float* __restrict__ z,
                                                 const float* __restrict__ w1, const float* __restrict__ b1,
                                                 const float* __restrict__ w2, const float* __restrict__ b2,
                                                 const float* __restrict__ w3, const float* __restrict__ b3,
                                                 float* __restrict__ out) {
  __shared__ float zs[Z_DIM];
  __shared__ float h1[128];
  __shared__ float red[128][2];
  __shared__ float y2[2];
  const int g = blockIdx.x;
  const int t = threadIdx.x;
  for (int i = t; i < Z_DIM; i += 128) zs[i] = z[(size_t)g * Z_DIM + i];
  __syncthreads();

  float acc = b1[t];
  for (int k = 0; k < Z_DIM; ++k) acc += zs[k] * w1[(size_t)k * 128 + t];
  h1[t] = fmaxf(acc, 0.f);
  __syncthreads();

  red[t][0] = h1[t] * w2[t * 2 + 0];
  red[t][1] = h1[t] * w2[t * 2 + 1];
  __syncthreads();
  if (t < 2) {
    float s = b2[t];
    for (int k = 0; k < 128; ++k) s += red[k][t];
    y2[t] = fmaxf(s, 0.f);
  }
  __syncthreads();
  if (t == 0) {
    const float z0 = y2[0] * w3[0] + y2[1] * w3[2] + b3[0];
    const float z1 = y2[0] * w3[1] + y2[1] * w3[3] + b3[1];
    const float m  = fmaxf(z0, z1);
    const float lse = m + logf(expf(z0 - m) + expf(z1 - m));
    out[g * 2 + 0] = z0 - lse;
    out[g * 2 + 1] = z1 - lse;
  }
}

// ---------------- launch ----------------

extern "C" void kernel_launch(void* const* d_in, const int* in_sizes, int n_in,
                              void* d_out, int out_size, void* d_ws, size_t ws_size,
                              hipStream_t stream) {
  (void)in_sizes; (void)n_in; (void)out_size; (void)ws_size;
  const float* x        = (const float*)d_in[0];
  const int*   eidx     = (const int*)d_in[1];
  const int*   batch    = (const int*)d_in[2];
  const float* eattr    = (const float*)d_in[3];
  const float* w_rel1   = (const float*)d_in[4];
  const float* b_rel1   = (const float*)d_in[5];
  const float* w_root1  = (const float*)d_in[6];
  const float* w_rel2   = (const float*)d_in[7];
  const float* b_rel2   = (const float*)d_in[8];
  const float* w_root2  = (const float*)d_in[9];
  const float* w_rel3   = (const float*)d_in[10];
  const float* b_rel3   = (const float*)d_in[11];
  const float* w_root3  = (const float*)d_in[12];
  const float* gamma1   = (const float*)d_in[13];
  const float* beta1    = (const float*)d_in[14];
  const float* gamma2   = (const float*)d_in[15];
  const float* beta2    = (const float*)d_in[16];
  const float* gamma3   = (const float*)d_in[17];
  const float* beta3    = (const float*)d_in[18];
  const float* w_lin1   = (const float*)d_in[19];
  const float* b_lin1   = (const float*)d_in[20];
  const float* w_lin2   = (const float*)d_in[21];
  const float* b_lin2   = (const float*)d_in[22];
  const float* w_lin3   = (const float*)d_in[23];
  const float* b_lin3   = (const float*)d_in[24];

  const int* src = eidx;
  const int* dst = eidx + N_EDGES;
  float* outp = (float*)d_out;

  char* ws = (char*)d_ws;
  size_t off = 0;
  auto alloc = [&](size_t bytes) -> void* {
    void* p = ws + off;
    off += (bytes + 255) & ~(size_t)255;
    return p;
  };
  int*   rowptr = (int*)alloc((N_NODES + 1) * sizeof(int));
  int*   cursor = (int*)alloc(N_NODES * sizeof(int));
  int*   gptr   = (int*)alloc((N_GRAPH + 1) * sizeof(int));
  int*   gcnt   = (int*)alloc(N_GRAPH * sizeof(int));
  int*   esrc   = (int*)alloc(N_EDGES * sizeof(int));
  float* eww    = (float*)alloc(N_EDGES * sizeof(float));
  float* sums   = (float*)alloc(4 * 384 * sizeof(float));
  float* zbuf   = (float*)alloc((size_t)N_GRAPH * Z_DIM * sizeof(float));
  unsigned short* xb   = (unsigned short*)alloc((size_t)M_PAD * 128 * 2);
  unsigned short* H1   = (unsigned short*)alloc((size_t)M_PAD * 128 * 2);
  unsigned short* H2   = (unsigned short*)alloc((size_t)M_PAD * 256 * 2);
  unsigned short* H3   = (unsigned short*)alloc((size_t)M_PAD * 384 * 2);
  unsigned short* aggb = (unsigned short*)alloc((size_t)M_PAD * 256 * 2);
  float* hpre = (float*)alloc((size_t)N_NODES * 384 * sizeof(float));
  unsigned short* wt1 = (unsigned short*)alloc((size_t)128 * 256 * 2);
  unsigned short* wt2 = (unsigned short*)alloc((size_t)256 * 256 * 2);
  unsigned short* wt3 = (unsigned short*)alloc((size_t)384 * 512 * 2);

  const int EB = (N_EDGES + 255) / 256;
  const int NB = (N_NODES + 255) / 256;
  const int RB = (N_NODES + 63) / 64;   // row-chunk blocks for bn_apply_pool

  // ---- CSR by dst ----
  hipMemsetAsync(cursor, 0, N_NODES * sizeof(int), stream);
  hist_kernel<<<EB, 256, 0, stream>>>(dst, cursor, N_EDGES);
  scan_kernel<<<1, 1024, 0, stream>>>(cursor, rowptr, N_NODES);
  hipMemsetAsync(cursor, 0, N_NODES * sizeof(int), stream);
  bucket_kernel<<<EB, 256, 0, stream>>>(src, dst, eattr, rowptr, cursor, esrc, eww, N_EDGES);

  // ---- graph segment pointers ----
  hipMemsetAsync(gcnt, 0, N_GRAPH * sizeof(int), stream);
  hist_kernel<<<NB, 256, 0, stream>>>(batch, gcnt, N_NODES);
  scan_kernel<<<1, 1024, 0, stream>>>(gcnt, gptr, N_GRAPH);

  // ---- prep ----
  hipMemsetAsync(zbuf, 0, (size_t)N_GRAPH * Z_DIM * sizeof(float), stream);
  cast_bf16_kernel<<<(N_NODES * 128 / 2 + 255) / 256, 256, 0, stream>>>(x, xb, N_NODES * 128 / 2);
  wt_build_kernel<<<128, 256, 0, stream>>>(w_rel1, w_root1, wt1, 128, 128);
  wt_build_kernel<<<256, 256, 0, stream>>>(w_rel2, w_root2, wt2, 128, 256);
  wt_build_kernel<<<384, 256, 0, stream>>>(w_rel3, w_root3, wt3, 256, 384);

  const int aggBlocks = (N_NODES * 64 + 255) / 256;
  const int MB = M_PAD / 128;

  // ---- layer 1: 128 -> 128 ----
  agg_bf16_kernel<128><<<aggBlocks, 256, 0, stream>>>(xb, rowptr, esrc, eww, aggb);
  gemm_mfma_kernel<<<dim3(MB, 1), 256, 0, stream>>>(aggb, xb, wt1, b_rel1, hpre,
                                                    N_NODES, 128, 128);
  hipMemsetAsync(sums, 0, 4 * 128 * sizeof(float), stream);
  bn_stats_kernel<<<dim3(1, 256), 128, 0, stream>>>(hpre, sums, N_NODES, 128);
  bn_finalize_kernel<<<1, 128, 0, stream>>>(sums, gamma1, beta1, N_NODES, 128);
  bn_apply_pool_kernel<<<dim3(RB, 1), 128, 0, stream>>>(hpre, sums, H1, batch, zbuf,
                                                        N_NODES, 128, 0);
  pool_finalize_kernel<<<(N_GRAPH * 128 + 255) / 256, 256, 0, stream>>>(zbuf, gptr, 128, 0);

  // ---- layer 2: 128 -> 256 ----
  agg_bf16_kernel<128><<<aggBlocks, 256, 0, stream>>>(H1, rowptr, esrc, eww, aggb);
  gemm_mfma_kernel<<<dim3(MB, 2), 256, 0, stream>>>(aggb, H1, wt2, b_rel2, hpre,
                                                    N_NODES, 128, 256);
  hipMemsetAsync(sums, 0, 4 * 256 * sizeof(float), stream);
  bn_stats_kernel<<<dim3(2, 256), 128, 0, stream>>>(hpre, sums, N_NODES, 256);
  bn_finalize_kernel<<<1, 256, 0, stream>>>(sums, gamma2, beta2, N_NODES, 256);
  bn_apply_pool_kernel<<<dim3(RB, 2), 128, 0, stream>>>(hpre, sums, H2, batch, zbuf,
                                                        N_NODES, 256, 384);
  pool_finalize_kernel<<<(N_GRAPH * 256 + 255) / 256, 256, 0, stream>>>(zbuf, gptr, 256, 384);

  // ---- layer 3: 256 -> 384 ----
  agg_bf16_kernel<256><<<aggBlocks, 256, 0, stream>>>(H2, rowptr, esrc, eww, aggb);
  gemm_mfma_kernel<<<dim3(MB, 3), 256, 0, stream>>>(aggb, H2, wt3, b_rel3, hpre,
                                                    N_NODES, 256, 384);
  hipMemsetAsync(sums, 0, 4 * 384 * sizeof(float), stream);
  bn_stats_kernel<<<dim3(3, 256), 128, 0, stream>>>(hpre, sums, N_NODES, 384);
  bn_finalize_kernel<<<2, 256, 0, stream>>>(sums, gamma3, beta3, N_NODES, 384);
  bn_apply_pool_kernel<<<dim3(RB, 3), 128, 0, stream>>>(hpre, sums, H3, batch, zbuf,
                                                        N_NODES, 384, 1152);
  pool_finalize_kernel<<<(N_GRAPH * 384 + 255) / 256, 256, 0, stream>>>(zbuf, gptr, 384, 1152);

  // ---- FC head ----
  fc_kernel<<<N_GRAPH, 128, 0, stream>>>(zbuf, w_lin1, b_lin1, w_lin2, b_lin2, w_lin3, b_lin3,
                                         outp);
}

// Round 4
// 732.792 us; speedup vs baseline: 2.7520x; 1.4400x over previous
//
#include <hip/hip_runtime.h>
#include <cstdint>
#include <cstddef>

#define N_NODES 50000
#define M_PAD   50048   // 391 * 128
#define N_EDGES 800000
#define N_GRAPH 256
#define Z_DIM   2304

static constexpr float LEAKY  = 0.01f;
static constexpr float BN_EPS = 1e-5f;

typedef short short8 __attribute__((ext_vector_type(8)));
typedef float floatx4 __attribute__((ext_vector_type(4)));

__device__ __forceinline__ unsigned short f2b(float f) {
  union { float f; unsigned int u; } v; v.f = f;
  unsigned int u = v.u;
  unsigned int r = (u + 0x7FFFu + ((u >> 16) & 1u)) >> 16;
  return (unsigned short)r;
}
__device__ __forceinline__ float b2f(unsigned short h) {
  union { unsigned int u; float f; } v; v.u = ((unsigned int)h) << 16;
  return v.f;
}

// ---------------- CSR build ----------------

__global__ void hist_kernel(const int* __restrict__ idx, int* __restrict__ cnt, int n) {
  int i = blockIdx.x * blockDim.x + threadIdx.x;
  if (i < n) atomicAdd(&cnt[idx[i]], 1);
}

// ---- hierarchical scan: phase 1 (1024-elem tiles, 256 thr x 4) ----
__global__ __launch_bounds__(256) void scan1_kernel(const int* __restrict__ in,
                                                    int* __restrict__ out,
                                                    int* __restrict__ part, int n) {
  __shared__ int sm[256];
  const int t = threadIdx.x;
  const int base = blockIdx.x * 1024 + t * 4;
  int v0 = 0, v1 = 0, v2 = 0, v3 = 0;
  if (base + 3 < n) {
    int4 q = *(const int4*)(in + base);
    v0 = q.x; v1 = q.y; v2 = q.z; v3 = q.w;
  } else {
    if (base     < n) v0 = in[base];
    if (base + 1 < n) v1 = in[base + 1];
    if (base + 2 < n) v2 = in[base + 2];
  }
  const int tsum = v0 + v1 + v2 + v3;
  sm[t] = tsum;
  __syncthreads();
  for (int off = 1; off < 256; off <<= 1) {
    int x = (t >= off) ? sm[t - off] : 0;
    __syncthreads();
    sm[t] += x;
    __syncthreads();
  }
  const int excl = sm[t] - tsum;
  if (base     < n) out[base]     = excl;
  if (base + 1 < n) out[base + 1] = excl + v0;
  if (base + 2 < n) out[base + 2] = excl + v0 + v1;
  if (base + 3 < n) out[base + 3] = excl + v0 + v1 + v2;
  if (t == 255) part[blockIdx.x] = sm[255];
}

// ---- phase 2: scan block partials (nb <= 256), write grand total ----
__global__ __launch_bounds__(256) void scan2_kernel(int* __restrict__ part, int nb,
                                                    int* __restrict__ total_out) {
  __shared__ int sm[256];
  const int t = threadIdx.x;
  const int v = (t < nb) ? part[t] : 0;
  sm[t] = v;
  __syncthreads();
  for (int off = 1; off < 256; off <<= 1) {
    int x = (t >= off) ? sm[t - off] : 0;
    __syncthreads();
    sm[t] += x;
    __syncthreads();
  }
  if (t < nb) part[t] = sm[t] - v;
  if (t == 255) *total_out = sm[255];
}

// ---- phase 3: add tile offsets ----
__global__ void scan3_kernel(int* __restrict__ out, const int* __restrict__ part, int n) {
  int i = blockIdx.x * blockDim.x + threadIdx.x;
  if (i < n) out[i] += part[i >> 10];
}

__global__ void bucket_kernel(const int* __restrict__ src, const int* __restrict__ dst,
                              const float* __restrict__ ew, const int* __restrict__ rowptr,
                              int* __restrict__ cursor, int* __restrict__ esrc,
                              float* __restrict__ eww, int E) {
  int e = blockIdx.x * blockDim.x + threadIdx.x;
  if (e < E) {
    int d = dst[e];
    int p = rowptr[d] + atomicAdd(&cursor[d], 1);
    esrc[p] = src[e];
    eww[p]  = ew[e];
  }
}

// ---------------- prep: casts & weight transpose ----------------

__global__ void cast_bf16_kernel(const float* __restrict__ in,
                                 unsigned short* __restrict__ out, int npair) {
  int i = blockIdx.x * blockDim.x + threadIdx.x;
  if (i >= npair) return;
  float2 v = *(const float2*)(in + 2 * (size_t)i);
  ((unsigned int*)out)[i] = (unsigned int)f2b(v.x) | ((unsigned int)f2b(v.y) << 16);
}

__global__ void wt_build_kernel(const float* __restrict__ wrel, const float* __restrict__ wroot,
                                unsigned short* __restrict__ wt, int K, int N) {
  int n = blockIdx.x;
  int K2 = 2 * K;
  for (int k = threadIdx.x; k < K2; k += blockDim.x) {
    float v = (k < K) ? wrel[(size_t)k * N + n] : wroot[(size_t)(k - K) * N + n];
    wt[(size_t)n * K2 + k] = f2b(v);
  }
}

// ---------------- aggregation: one wave per dst node, 4-edge unrolled ----------------

template <int D>
__global__ void agg_bf16_kernel(const unsigned short* __restrict__ h,
                                const int* __restrict__ rowptr,
                                const int* __restrict__ esrc, const float* __restrict__ eww,
                                unsigned short* __restrict__ agg) {
  int gid  = blockIdx.x * blockDim.x + threadIdx.x;
  int node = gid >> 6;
  int lane = threadIdx.x & 63;
  if (node >= N_NODES) return;
  const int beg = rowptr[node], end = rowptr[node + 1];
  constexpr int NP = D / 128;
  float acc0[NP], acc1[NP];
#pragma unroll
  for (int i = 0; i < NP; ++i) { acc0[i] = 0.f; acc1[i] = 0.f; }

  int p = beg;
  for (; p + 4 <= end; p += 4) {
    const int s0 = esrc[p], s1 = esrc[p + 1], s2 = esrc[p + 2], s3 = esrc[p + 3];
    const float w0 = eww[p], w1 = eww[p + 1], w2 = eww[p + 2], w3 = eww[p + 3];
    const unsigned int* r0 = (const unsigned int*)(h + (size_t)s0 * D);
    const unsigned int* r1 = (const unsigned int*)(h + (size_t)s1 * D);
    const unsigned int* r2 = (const unsigned int*)(h + (size_t)s2 * D);
    const unsigned int* r3 = (const unsigned int*)(h + (size_t)s3 * D);
    unsigned int u0[NP], u1[NP], u2[NP], u3[NP];
#pragma unroll
    for (int i = 0; i < NP; ++i) {
      u0[i] = r0[lane + 64 * i];
      u1[i] = r1[lane + 64 * i];
      u2[i] = r2[lane + 64 * i];
      u3[i] = r3[lane + 64 * i];
    }
#pragma unroll
    for (int i = 0; i < NP; ++i) {
      acc0[i] += b2f((unsigned short)(u0[i] & 0xFFFF)) * w0
               + b2f((unsigned short)(u1[i] & 0xFFFF)) * w1
               + b2f((unsigned short)(u2[i] & 0xFFFF)) * w2
               + b2f((unsigned short)(u3[i] & 0xFFFF)) * w3;
      acc1[i] += b2f((unsigned short)(u0[i] >> 16)) * w0
               + b2f((unsigned short)(u1[i] >> 16)) * w1
               + b2f((unsigned short)(u2[i] >> 16)) * w2
               + b2f((unsigned short)(u3[i] >> 16)) * w3;
    }
  }
  for (; p < end; ++p) {
    const int   s = esrc[p];
    const float w = eww[p];
    const unsigned int* row = (const unsigned int*)(h + (size_t)s * D);
#pragma unroll
    for (int i = 0; i < NP; ++i) {
      unsigned int u = row[lane + 64 * i];
      acc0[i] += b2f((unsigned short)(u & 0xFFFF)) * w;
      acc1[i] += b2f((unsigned short)(u >> 16)) * w;
    }
  }
  unsigned int* o = (unsigned int*)(agg + (size_t)node * D);
#pragma unroll
  for (int i = 0; i < NP; ++i)
    o[lane + 64 * i] = (unsigned int)f2b(acc0[i]) | ((unsigned int)f2b(acc1[i]) << 16);
}

// ---------------- MFMA GEMM with fused BN-stats epilogue ----------------
// sums[0..N) += column sums of leaky(out); sums[N..2N) += column sum-of-squares.

__global__ __launch_bounds__(256) void gemm_mfma_kernel(
    const unsigned short* __restrict__ Aagg, const unsigned short* __restrict__ Ah,
    const unsigned short* __restrict__ Wt, const float* __restrict__ bias,
    float* __restrict__ out, float* __restrict__ sums, int M, int K, int N) {
  constexpr int LDA = 40;
  __shared__ unsigned short As[128 * LDA];
  __shared__ unsigned short Bs[128 * LDA];
  __shared__ float col_s[256];  // [0..128) colsum, [128..256) colsumsq

  const int m0 = blockIdx.x * 128;
  const int n0 = blockIdx.y * 128;
  const int t  = threadIdx.x;
  const int lane = t & 63;
  const int w    = t >> 6;
  const int wm   = (w & 1) * 64;
  const int wn   = (w >> 1) * 64;
  const int l16  = lane & 15;
  const int lq   = lane >> 4;
  const int K2   = 2 * K;

  col_s[t] = 0.f;  // visible after first __syncthreads in the k-loop

  floatx4 acc[4][4];
#pragma unroll
  for (int i = 0; i < 4; ++i)
#pragma unroll
    for (int j = 0; j < 4; ++j) acc[i][j] = (floatx4){0.f, 0.f, 0.f, 0.f};

  const int r0 = t >> 2;
  const int c80 = (t & 3) * 8;

  for (int k0 = 0; k0 < K2; k0 += 32) {
    const unsigned short* Asrc;
    int kbase;
    if (k0 < K) { Asrc = Aagg; kbase = k0; } else { Asrc = Ah; kbase = k0 - K; }

    short8 a0 = *(const short8*)(Asrc + (size_t)(m0 + r0) * K + kbase + c80);
    short8 a1 = *(const short8*)(Asrc + (size_t)(m0 + r0 + 64) * K + kbase + c80);
    short8 b0 = *(const short8*)(Wt + (size_t)(n0 + r0) * K2 + k0 + c80);
    short8 b1 = *(const short8*)(Wt + (size_t)(n0 + r0 + 64) * K2 + k0 + c80);

    __syncthreads();
    *(short8*)(As + r0 * LDA + c80)        = a0;
    *(short8*)(As + (r0 + 64) * LDA + c80) = a1;
    *(short8*)(Bs + r0 * LDA + c80)        = b0;
    *(short8*)(Bs + (r0 + 64) * LDA + c80) = b1;
    __syncthreads();

    short8 af[4], bfr[4];
#pragma unroll
    for (int i = 0; i < 4; ++i)
      af[i] = *(const short8*)(As + (wm + i * 16 + l16) * LDA + lq * 8);
#pragma unroll
    for (int j = 0; j < 4; ++j)
      bfr[j] = *(const short8*)(Bs + (wn + j * 16 + l16) * LDA + lq * 8);

#pragma unroll
    for (int i = 0; i < 4; ++i)
#pragma unroll
      for (int j = 0; j < 4; ++j)
        acc[i][j] = __builtin_amdgcn_mfma_f32_16x16x32_bf16(af[i], bfr[j], acc[i][j], 0, 0, 0);
  }

  float ts[4]  = {0.f, 0.f, 0.f, 0.f};
  float tss[4] = {0.f, 0.f, 0.f, 0.f};
#pragma unroll
  for (int i = 0; i < 4; ++i) {
    const int mbase = m0 + wm + i * 16 + lq * 4;
#pragma unroll
    for (int j = 0; j < 4; ++j) {
      const int n = n0 + wn + j * 16 + l16;
      const float bb = bias[n];
#pragma unroll
      for (int r = 0; r < 4; ++r) {
        const int m = mbase + r;
        if (m < M) {
          float v = acc[i][j][r] + bb;
          v = v > 0.f ? v : LEAKY * v;
          out[(size_t)m * N + n] = v;
          ts[j]  += v;
          tss[j] += v * v;
        }
      }
    }
  }
  // reduce the 4 lq sub-rows per channel, then combine across waves in LDS
#pragma unroll
  for (int j = 0; j < 4; ++j) {
    float a = ts[j], b = tss[j];
    a += __shfl_xor(a, 16); a += __shfl_xor(a, 32);
    b += __shfl_xor(b, 16); b += __shfl_xor(b, 32);
    if (lq == 0) {
      const int ci = wn + j * 16 + l16;
      atomicAdd(&col_s[ci], a);
      atomicAdd(&col_s[128 + ci], b);
    }
  }
  __syncthreads();
  if (t < 128) {
    atomicAdd(&sums[n0 + t], col_s[t]);
    atomicAdd(&sums[N + n0 + t], col_s[128 + t]);
  }
}

// ---------------- BN finalize ----------------

__global__ void bn_finalize_kernel(float* __restrict__ sums, const float* __restrict__ gamma,
                                   const float* __restrict__ beta, int n, int C) {
  int c = blockIdx.x * blockDim.x + threadIdx.x;
  if (c >= C) return;
  const float inv_n = 1.f / (float)n;
  const float mu  = sums[c] * inv_n;
  const float var = sums[C + c] * inv_n - mu * mu;
  const float sc  = rsqrtf(var + BN_EPS) * gamma[c];
  sums[2 * C + c] = sc;
  sums[3 * C + c] = beta[c] - mu * sc;
}

// ---------------- fused BN-apply + pooling ----------------

__device__ __forceinline__ void pool_flush(float* __restrict__ z, int g, int C, int zoff,
                                           int c, float mx, float s) {
  float* zg = z + (size_t)g * Z_DIM + zoff;
  unsigned key = __float_as_uint(mx);
  key ^= (key & 0x80000000u) ? 0xFFFFFFFFu : 0x80000000u;
  atomicMax((unsigned int*)(zg + c), key);
  atomicAdd(zg + 2 * C + c, s);
}

__global__ __launch_bounds__(128) void bn_apply_pool_kernel(
    const float* __restrict__ hpre, const float* __restrict__ sums,
    unsigned short* __restrict__ H, const int* __restrict__ batch,
    float* __restrict__ z, int n, int C, int zoff) {
  __shared__ int bs[64];
  const int c  = blockIdx.y * 128 + threadIdx.x;
  const int r0 = blockIdx.x * 64;
  const int r1 = min(n, r0 + 64);
  if (threadIdx.x < 64 && r0 + (int)threadIdx.x < n) bs[threadIdx.x] = batch[r0 + threadIdx.x];
  __syncthreads();
  const float sc = sums[2 * C + c];
  const float sh = sums[3 * C + c];
  int   cur_g = bs[0];
  float mx = -3.4e38f, s = 0.f;
  for (int r = r0; r < r1; ++r) {
    const int g = bs[r - r0];
    if (g != cur_g) {
      pool_flush(z, cur_g, C, zoff, c, mx, s);
      mx = -3.4e38f; s = 0.f; cur_g = g;
    }
    const float v = hpre[(size_t)r * C + c] * sc + sh;
    H[(size_t)r * C + c] = f2b(v);
    mx = fmaxf(mx, v);
    s += v;
  }
  pool_flush(z, cur_g, C, zoff, c, mx, s);
}

__global__ void pool_finalize_kernel(float* __restrict__ z, const int* __restrict__ gptr,
                                     int C, int zoff) {
  int i = blockIdx.x * blockDim.x + threadIdx.x;
  if (i >= N_GRAPH * C) return;
  int g = i / C, c = i % C;
  int cnt = gptr[g + 1] - gptr[g];
  float* zg = z + (size_t)g * Z_DIM + zoff;
  unsigned key = __float_as_uint(zg[c]);
  key ^= (key & 0x80000000u) ? 0x80000000u : 0xFFFFFFFFu;
  float mx = __uint_as_float(key);
  float sum = zg[2 * C + c];
  zg[c]     = (cnt > 0) ? mx : 0.f;
  zg[C + c] = sum / (float)(cnt > 0 ? cnt : 1);
}

// ---------------- FC head ----------------

__global__ __launch_bounds__(128) void fc_kernel(const float* __restrict__ z,
                                                 const float* __restrict__ w1, const float* __restrict__ b1,
                                                 const float* __restrict__ w2, const float* __restrict__ b2,
                                                 const float* __restrict__ w3, const float* __restrict__ b3,
                                                 float* __restrict__ out) {
  __shared__ float zs[Z_DIM];
  __shared__ float h1[128];
  __shared__ float red[128][2];
  __shared__ float y2[2];
  const int g = blockIdx.x;
  const int t = threadIdx.x;
  for (int i = t; i < Z_DIM; i += 128) zs[i] = z[(size_t)g * Z_DIM + i];
  __syncthreads();

  float acc = b1[t];
  for (int k = 0; k < Z_DIM; ++k) acc += zs[k] * w1[(size_t)k * 128 + t];
  h1[t] = fmaxf(acc, 0.f);
  __syncthreads();

  red[t][0] = h1[t] * w2[t * 2 + 0];
  red[t][1] = h1[t] * w2[t * 2 + 1];
  __syncthreads();
  if (t < 2) {
    float s = b2[t];
    for (int k = 0; k < 128; ++k) s += red[k][t];
    y2[t] = fmaxf(s, 0.f);
  }
  __syncthreads();
  if (t == 0) {
    const float z0 = y2[0] * w3[0] + y2[1] * w3[2] + b3[0];
    const float z1 = y2[0] * w3[1] + y2[1] * w3[3] + b3[1];
    const float m  = fmaxf(z0, z1);
    const float lse = m + logf(expf(z0 - m) + expf(z1 - m));
    out[g * 2 + 0] = z0 - lse;
    out[g * 2 + 1] = z1 - lse;
  }
}

// ---------------- launch ----------------

extern "C" void kernel_launch(void* const* d_in, const int* in_sizes, int n_in,
                              void* d_out, int out_size, void* d_ws, size_t ws_size,
                              hipStream_t stream) {
  (void)in_sizes; (void)n_in; (void)out_size; (void)ws_size;
  const float* x        = (const float*)d_in[0];
  const int*   eidx     = (const int*)d_in[1];
  const int*   batch    = (const int*)d_in[2];
  const float* eattr    = (const float*)d_in[3];
  const float* w_rel1   = (const float*)d_in[4];
  const float* b_rel1   = (const float*)d_in[5];
  const float* w_root1  = (const float*)d_in[6];
  const float* w_rel2   = (const float*)d_in[7];
  const float* b_rel2   = (const float*)d_in[8];
  const float* w_root2  = (const float*)d_in[9];
  const float* w_rel3   = (const float*)d_in[10];
  const float* b_rel3   = (const float*)d_in[11];
  const float* w_root3  = (const float*)d_in[12];
  const float* gamma1   = (const float*)d_in[13];
  const float* beta1    = (const float*)d_in[14];
  const float* gamma2   = (const float*)d_in[15];
  const float* beta2    = (const float*)d_in[16];
  const float* gamma3   = (const float*)d_in[17];
  const float* beta3    = (const float*)d_in[18];
  const float* w_lin1   = (const float*)d_in[19];
  const float* b_lin1   = (const float*)d_in[20];
  const float* w_lin2   = (const float*)d_in[21];
  const float* b_lin2   = (const float*)d_in[22];
  const float* w_lin3   = (const float*)d_in[23];
  const float* b_lin3   = (const float*)d_in[24];

  const int* src = eidx;
  const int* dst = eidx + N_EDGES;
  float* outp = (float*)d_out;

  char* ws = (char*)d_ws;
  size_t off = 0;
  auto alloc = [&](size_t bytes) -> void* {
    void* p = ws + off;
    off += (bytes + 255) & ~(size_t)255;
    return p;
  };
  int*   rowptr = (int*)alloc((N_NODES + 1) * sizeof(int));
  int*   cursor = (int*)alloc(N_NODES * sizeof(int));
  int*   gptr   = (int*)alloc((N_GRAPH + 1) * sizeof(int));
  int*   gcnt   = (int*)alloc(N_GRAPH * sizeof(int));
  int*   part   = (int*)alloc(256 * sizeof(int));
  int*   part2  = (int*)alloc(256 * sizeof(int));
  int*   esrc   = (int*)alloc(N_EDGES * sizeof(int));
  float* eww    = (float*)alloc(N_EDGES * sizeof(float));
  float* sums   = (float*)alloc(4 * 384 * sizeof(float));
  float* zbuf   = (float*)alloc((size_t)N_GRAPH * Z_DIM * sizeof(float));
  unsigned short* xb   = (unsigned short*)alloc((size_t)M_PAD * 128 * 2);
  unsigned short* H1   = (unsigned short*)alloc((size_t)M_PAD * 128 * 2);
  unsigned short* H2   = (unsigned short*)alloc((size_t)M_PAD * 256 * 2);
  unsigned short* H3   = (unsigned short*)alloc((size_t)M_PAD * 384 * 2);
  unsigned short* aggb = (unsigned short*)alloc((size_t)M_PAD * 256 * 2);
  float* hpre = (float*)alloc((size_t)N_NODES * 384 * sizeof(float));
  unsigned short* wt1 = (unsigned short*)alloc((size_t)128 * 256 * 2);
  unsigned short* wt2 = (unsigned short*)alloc((size_t)256 * 256 * 2);
  unsigned short* wt3 = (unsigned short*)alloc((size_t)384 * 512 * 2);

  const int EB = (N_EDGES + 255) / 256;
  const int NB = (N_NODES + 255) / 256;
  const int RB = (N_NODES + 63) / 64;
  const int SB = (N_NODES + 1023) / 1024;  // 49 scan tiles

  // ---- CSR by dst ----
  hipMemsetAsync(cursor, 0, N_NODES * sizeof(int), stream);
  hist_kernel<<<EB, 256, 0, stream>>>(dst, cursor, N_EDGES);
  scan1_kernel<<<SB, 256, 0, stream>>>(cursor, rowptr, part, N_NODES);
  scan2_kernel<<<1, 256, 0, stream>>>(part, SB, rowptr + N_NODES);
  scan3_kernel<<<NB, 256, 0, stream>>>(rowptr, part, N_NODES);
  hipMemsetAsync(cursor, 0, N_NODES * sizeof(int), stream);
  bucket_kernel<<<EB, 256, 0, stream>>>(src, dst, eattr, rowptr, cursor, esrc, eww, N_EDGES);

  // ---- graph segment pointers ----
  hipMemsetAsync(gcnt, 0, N_GRAPH * sizeof(int), stream);
  hist_kernel<<<NB, 256, 0, stream>>>(batch, gcnt, N_NODES);
  scan1_kernel<<<1, 256, 0, stream>>>(gcnt, gptr, part2, N_GRAPH);
  scan2_kernel<<<1, 256, 0, stream>>>(part2, 1, gptr + N_GRAPH);

  // ---- prep ----
  hipMemsetAsync(zbuf, 0, (size_t)N_GRAPH * Z_DIM * sizeof(float), stream);
  cast_bf16_kernel<<<(N_NODES * 128 / 2 + 255) / 256, 256, 0, stream>>>(x, xb, N_NODES * 128 / 2);
  wt_build_kernel<<<128, 256, 0, stream>>>(w_rel1, w_root1, wt1, 128, 128);
  wt_build_kernel<<<256, 256, 0, stream>>>(w_rel2, w_root2, wt2, 128, 256);
  wt_build_kernel<<<384, 256, 0, stream>>>(w_rel3, w_root3, wt3, 256, 384);

  const int aggBlocks = (N_NODES * 64 + 255) / 256;
  const int MB = M_PAD / 128;

  // ---- layer 1: 128 -> 128 ----
  agg_bf16_kernel<128><<<aggBlocks, 256, 0, stream>>>(xb, rowptr, esrc, eww, aggb);
  hipMemsetAsync(sums, 0, 4 * 128 * sizeof(float), stream);
  gemm_mfma_kernel<<<dim3(MB, 1), 256, 0, stream>>>(aggb, xb, wt1, b_rel1, hpre, sums,
                                                    N_NODES, 128, 128);
  bn_finalize_kernel<<<1, 128, 0, stream>>>(sums, gamma1, beta1, N_NODES, 128);
  bn_apply_pool_kernel<<<dim3(RB, 1), 128, 0, stream>>>(hpre, sums, H1, batch, zbuf,
                                                        N_NODES, 128, 0);
  pool_finalize_kernel<<<(N_GRAPH * 128 + 255) / 256, 256, 0, stream>>>(zbuf, gptr, 128, 0);

  // ---- layer 2: 128 -> 256 ----
  agg_bf16_kernel<128><<<aggBlocks, 256, 0, stream>>>(H1, rowptr, esrc, eww, aggb);
  hipMemsetAsync(sums, 0, 4 * 256 * sizeof(float), stream);
  gemm_mfma_kernel<<<dim3(MB, 2), 256, 0, stream>>>(aggb, H1, wt2, b_rel2, hpre, sums,
                                                    N_NODES, 128, 256);
  bn_finalize_kernel<<<1, 256, 0, stream>>>(sums, gamma2, beta2, N_NODES, 256);
  bn_apply_pool_kernel<<<dim3(RB, 2), 128, 0, stream>>>(hpre, sums, H2, batch, zbuf,
                                                        N_NODES, 256, 384);
  pool_finalize_kernel<<<(N_GRAPH * 256 + 255) / 256, 256, 0, stream>>>(zbuf, gptr, 256, 384);

  // ---- layer 3: 256 -> 384 ----
  agg_bf16_kernel<256><<<aggBlocks, 256, 0, stream>>>(H2, rowptr, esrc, eww, aggb);
  hipMemsetAsync(sums, 0, 4 * 384 * sizeof(float), stream);
  gemm_mfma_kernel<<<dim3(MB, 3), 256, 0, stream>>>(aggb, H2, wt3, b_rel3, hpre, sums,
                                                    N_NODES, 256, 384);
  bn_finalize_kernel<<<2, 256, 0, stream>>>(sums, gamma3, beta3, N_NODES, 384);
  bn_apply_pool_kernel<<<dim3(RB, 3), 128, 0, stream>>>(hpre, sums, H3, batch, zbuf,
                                                        N_NODES, 384, 1152);
  pool_finalize_kernel<<<(N_GRAPH * 384 + 255) / 256, 256, 0, stream>>>(zbuf, gptr, 384, 1152);

  // ---- FC head ----
  fc_kernel<<<N_GRAPH, 128, 0, stream>>>(zbuf, w_lin1, b_lin1, w_lin2, b_lin2, w_lin3, b_lin3,
                                         outp);
}

// Round 5
// 695.386 us; speedup vs baseline: 2.9001x; 1.0538x over previous
//
#include <hip/hip_runtime.h>
#include <cstdint>
#include <cstddef>

#define N_NODES 50000
#define M_PAD   50048   // 391 * 128
#define N_EDGES 800000
#define N_GRAPH 256
#define Z_DIM   2304

static constexpr float LEAKY  = 0.01f;
static constexpr float BN_EPS = 1e-5f;

typedef short short8 __attribute__((ext_vector_type(8)));
typedef float floatx4 __attribute__((ext_vector_type(4)));

__device__ __forceinline__ unsigned short f2b(float f) {
  union { float f; unsigned int u; } v; v.f = f;
  unsigned int u = v.u;
  unsigned int r = (u + 0x7FFFu + ((u >> 16) & 1u)) >> 16;
  return (unsigned short)r;
}
__device__ __forceinline__ float b2f(unsigned short h) {
  union { unsigned int u; float f; } v; v.u = ((unsigned int)h) << 16;
  return v.f;
}

// ---------------- CSR build ----------------

__global__ void hist_kernel(const int* __restrict__ idx, int* __restrict__ cnt, int n) {
  int i = blockIdx.x * blockDim.x + threadIdx.x;
  if (i < n) atomicAdd(&cnt[idx[i]], 1);
}

__global__ __launch_bounds__(256) void scan1_kernel(const int* __restrict__ in,
                                                    int* __restrict__ out,
                                                    int* __restrict__ part, int n) {
  __shared__ int sm[256];
  const int t = threadIdx.x;
  const int base = blockIdx.x * 1024 + t * 4;
  int v0 = 0, v1 = 0, v2 = 0, v3 = 0;
  if (base + 3 < n) {
    int4 q = *(const int4*)(in + base);
    v0 = q.x; v1 = q.y; v2 = q.z; v3 = q.w;
  } else {
    if (base     < n) v0 = in[base];
    if (base + 1 < n) v1 = in[base + 1];
    if (base + 2 < n) v2 = in[base + 2];
  }
  const int tsum = v0 + v1 + v2 + v3;
  sm[t] = tsum;
  __syncthreads();
  for (int off = 1; off < 256; off <<= 1) {
    int x = (t >= off) ? sm[t - off] : 0;
    __syncthreads();
    sm[t] += x;
    __syncthreads();
  }
  const int excl = sm[t] - tsum;
  if (base     < n) out[base]     = excl;
  if (base + 1 < n) out[base + 1] = excl + v0;
  if (base + 2 < n) out[base + 2] = excl + v0 + v1;
  if (base + 3 < n) out[base + 3] = excl + v0 + v1 + v2;
  if (t == 255) part[blockIdx.x] = sm[255];
}

__global__ __launch_bounds__(256) void scan2_kernel(int* __restrict__ part, int nb,
                                                    int* __restrict__ total_out) {
  __shared__ int sm[256];
  const int t = threadIdx.x;
  const int v = (t < nb) ? part[t] : 0;
  sm[t] = v;
  __syncthreads();
  for (int off = 1; off < 256; off <<= 1) {
    int x = (t >= off) ? sm[t - off] : 0;
    __syncthreads();
    sm[t] += x;
    __syncthreads();
  }
  if (t < nb) part[t] = sm[t] - v;
  if (t == 255) *total_out = sm[255];
}

__global__ void scan3_kernel(int* __restrict__ out, const int* __restrict__ part, int n) {
  int i = blockIdx.x * blockDim.x + threadIdx.x;
  if (i < n) out[i] += part[i >> 10];
}

__global__ void bucket_kernel(const int* __restrict__ src, const int* __restrict__ dst,
                              const float* __restrict__ ew, const int* __restrict__ rowptr,
                              int* __restrict__ cursor, int* __restrict__ esrc,
                              float* __restrict__ eww, int E) {
  int e = blockIdx.x * blockDim.x + threadIdx.x;
  if (e < E) {
    int d = dst[e];
    int p = rowptr[d] + atomicAdd(&cursor[d], 1);
    esrc[p] = src[e];
    eww[p]  = ew[e];
  }
}

// ---------------- prep: casts & weight transpose ----------------

__global__ void cast_bf16_kernel(const float* __restrict__ in,
                                 unsigned short* __restrict__ out, int npair) {
  int i = blockIdx.x * blockDim.x + threadIdx.x;
  if (i >= npair) return;
  float2 v = *(const float2*)(in + 2 * (size_t)i);
  ((unsigned int*)out)[i] = (unsigned int)f2b(v.x) | ((unsigned int)f2b(v.y) << 16);
}

__global__ void wt_build_kernel(const float* __restrict__ wrel, const float* __restrict__ wroot,
                                unsigned short* __restrict__ wt, int K, int N) {
  int n = blockIdx.x;
  int K2 = 2 * K;
  for (int k = threadIdx.x; k < K2; k += blockDim.x) {
    float v = (k < K) ? wrel[(size_t)k * N + n] : wroot[(size_t)(k - K) * N + n];
    wt[(size_t)n * K2 + k] = f2b(v);
  }
}

// ---------------- aggregation: one wave per dst node, 4-edge unrolled ----------------

template <int D>
__global__ void agg_bf16_kernel(const unsigned short* __restrict__ h,
                                const int* __restrict__ rowptr,
                                const int* __restrict__ esrc, const float* __restrict__ eww,
                                unsigned short* __restrict__ agg) {
  int gid  = blockIdx.x * blockDim.x + threadIdx.x;
  int node = gid >> 6;
  int lane = threadIdx.x & 63;
  if (node >= N_NODES) return;
  const int beg = rowptr[node], end = rowptr[node + 1];
  constexpr int NP = D / 128;
  float acc0[NP], acc1[NP];
#pragma unroll
  for (int i = 0; i < NP; ++i) { acc0[i] = 0.f; acc1[i] = 0.f; }

  int p = beg;
  for (; p + 4 <= end; p += 4) {
    const int s0 = esrc[p], s1 = esrc[p + 1], s2 = esrc[p + 2], s3 = esrc[p + 3];
    const float w0 = eww[p], w1 = eww[p + 1], w2 = eww[p + 2], w3 = eww[p + 3];
    const unsigned int* r0 = (const unsigned int*)(h + (size_t)s0 * D);
    const unsigned int* r1 = (const unsigned int*)(h + (size_t)s1 * D);
    const unsigned int* r2 = (const unsigned int*)(h + (size_t)s2 * D);
    const unsigned int* r3 = (const unsigned int*)(h + (size_t)s3 * D);
    unsigned int u0[NP], u1[NP], u2[NP], u3[NP];
#pragma unroll
    for (int i = 0; i < NP; ++i) {
      u0[i] = r0[lane + 64 * i];
      u1[i] = r1[lane + 64 * i];
      u2[i] = r2[lane + 64 * i];
      u3[i] = r3[lane + 64 * i];
    }
#pragma unroll
    for (int i = 0; i < NP; ++i) {
      acc0[i] += b2f((unsigned short)(u0[i] & 0xFFFF)) * w0
               + b2f((unsigned short)(u1[i] & 0xFFFF)) * w1
               + b2f((unsigned short)(u2[i] & 0xFFFF)) * w2
               + b2f((unsigned short)(u3[i] & 0xFFFF)) * w3;
      acc1[i] += b2f((unsigned short)(u0[i] >> 16)) * w0
               + b2f((unsigned short)(u1[i] >> 16)) * w1
               + b2f((unsigned short)(u2[i] >> 16)) * w2
               + b2f((unsigned short)(u3[i] >> 16)) * w3;
    }
  }
  for (; p < end; ++p) {
    const int   s = esrc[p];
    const float w = eww[p];
    const unsigned int* row = (const unsigned int*)(h + (size_t)s * D);
#pragma unroll
    for (int i = 0; i < NP; ++i) {
      unsigned int u = row[lane + 64 * i];
      acc0[i] += b2f((unsigned short)(u & 0xFFFF)) * w;
      acc1[i] += b2f((unsigned short)(u >> 16)) * w;
    }
  }
  unsigned int* o = (unsigned int*)(agg + (size_t)node * D);
#pragma unroll
  for (int i = 0; i < NP; ++i)
    o[lane + 64 * i] = (unsigned int)f2b(acc0[i]) | ((unsigned int)f2b(acc1[i]) << 16);
}

// ---------------- MFMA GEMM with fused BN-stats epilogue ----------------

__global__ __launch_bounds__(256) void gemm_mfma_kernel(
    const unsigned short* __restrict__ Aagg, const unsigned short* __restrict__ Ah,
    const unsigned short* __restrict__ Wt, const float* __restrict__ bias,
    float* __restrict__ out, float* __restrict__ sums, int M, int K, int N) {
  constexpr int LDA = 40;
  __shared__ unsigned short As[128 * LDA];
  __shared__ unsigned short Bs[128 * LDA];
  __shared__ float col_s[256];

  const int m0 = blockIdx.x * 128;
  const int n0 = blockIdx.y * 128;
  const int t  = threadIdx.x;
  const int lane = t & 63;
  const int w    = t >> 6;
  const int wm   = (w & 1) * 64;
  const int wn   = (w >> 1) * 64;
  const int l16  = lane & 15;
  const int lq   = lane >> 4;
  const int K2   = 2 * K;

  col_s[t] = 0.f;

  floatx4 acc[4][4];
#pragma unroll
  for (int i = 0; i < 4; ++i)
#pragma unroll
    for (int j = 0; j < 4; ++j) acc[i][j] = (floatx4){0.f, 0.f, 0.f, 0.f};

  const int r0 = t >> 2;
  const int c80 = (t & 3) * 8;

  for (int k0 = 0; k0 < K2; k0 += 32) {
    const unsigned short* Asrc;
    int kbase;
    if (k0 < K) { Asrc = Aagg; kbase = k0; } else { Asrc = Ah; kbase = k0 - K; }

    short8 a0 = *(const short8*)(Asrc + (size_t)(m0 + r0) * K + kbase + c80);
    short8 a1 = *(const short8*)(Asrc + (size_t)(m0 + r0 + 64) * K + kbase + c80);
    short8 b0 = *(const short8*)(Wt + (size_t)(n0 + r0) * K2 + k0 + c80);
    short8 b1 = *(const short8*)(Wt + (size_t)(n0 + r0 + 64) * K2 + k0 + c80);

    __syncthreads();
    *(short8*)(As + r0 * LDA + c80)        = a0;
    *(short8*)(As + (r0 + 64) * LDA + c80) = a1;
    *(short8*)(Bs + r0 * LDA + c80)        = b0;
    *(short8*)(Bs + (r0 + 64) * LDA + c80) = b1;
    __syncthreads();

    short8 af[4], bfr[4];
#pragma unroll
    for (int i = 0; i < 4; ++i)
      af[i] = *(const short8*)(As + (wm + i * 16 + l16) * LDA + lq * 8);
#pragma unroll
    for (int j = 0; j < 4; ++j)
      bfr[j] = *(const short8*)(Bs + (wn + j * 16 + l16) * LDA + lq * 8);

#pragma unroll
    for (int i = 0; i < 4; ++i)
#pragma unroll
      for (int j = 0; j < 4; ++j)
        acc[i][j] = __builtin_amdgcn_mfma_f32_16x16x32_bf16(af[i], bfr[j], acc[i][j], 0, 0, 0);
  }

  float ts[4]  = {0.f, 0.f, 0.f, 0.f};
  float tss[4] = {0.f, 0.f, 0.f, 0.f};
#pragma unroll
  for (int i = 0; i < 4; ++i) {
    const int mbase = m0 + wm + i * 16 + lq * 4;
#pragma unroll
    for (int j = 0; j < 4; ++j) {
      const int n = n0 + wn + j * 16 + l16;
      const float bb = bias[n];
#pragma unroll
      for (int r = 0; r < 4; ++r) {
        const int m = mbase + r;
        if (m < M) {
          float v = acc[i][j][r] + bb;
          v = v > 0.f ? v : LEAKY * v;
          out[(size_t)m * N + n] = v;
          ts[j]  += v;
          tss[j] += v * v;
        }
      }
    }
  }
#pragma unroll
  for (int j = 0; j < 4; ++j) {
    float a = ts[j], b = tss[j];
    a += __shfl_xor(a, 16); a += __shfl_xor(a, 32);
    b += __shfl_xor(b, 16); b += __shfl_xor(b, 32);
    if (lq == 0) {
      const int ci = wn + j * 16 + l16;
      atomicAdd(&col_s[ci], a);
      atomicAdd(&col_s[128 + ci], b);
    }
  }
  __syncthreads();
  if (t < 128) {
    atomicAdd(&sums[n0 + t], col_s[t]);
    atomicAdd(&sums[N + n0 + t], col_s[128 + t]);
  }
}

// ---------------- BN finalize ----------------

__global__ void bn_finalize_kernel(float* __restrict__ sums, const float* __restrict__ gamma,
                                   const float* __restrict__ beta, int n, int C) {
  int c = blockIdx.x * blockDim.x + threadIdx.x;
  if (c >= C) return;
  const float inv_n = 1.f / (float)n;
  const float mu  = sums[c] * inv_n;
  const float var = sums[C + c] * inv_n - mu * mu;
  const float sc  = rsqrtf(var + BN_EPS) * gamma[c];
  sums[2 * C + c] = sc;
  sums[3 * C + c] = beta[c] - mu * sc;
}

// ---------------- fused BN-apply + pooling ----------------

__device__ __forceinline__ void pool_flush(float* __restrict__ z, int g, int C, int zoff,
                                           int c, float mx, float s) {
  float* zg = z + (size_t)g * Z_DIM + zoff;
  unsigned key = __float_as_uint(mx);
  key ^= (key & 0x80000000u) ? 0xFFFFFFFFu : 0x80000000u;
  atomicMax((unsigned int*)(zg + c), key);
  atomicAdd(zg + 2 * C + c, s);
}

__global__ __launch_bounds__(128) void bn_apply_pool_kernel(
    const float* __restrict__ hpre, const float* __restrict__ sums,
    unsigned short* __restrict__ H, const int* __restrict__ batch,
    float* __restrict__ z, int n, int C, int zoff) {
  __shared__ int bs[64];
  const int c  = blockIdx.y * 128 + threadIdx.x;
  const int r0 = blockIdx.x * 64;
  const int r1 = min(n, r0 + 64);
  if (threadIdx.x < 64 && r0 + (int)threadIdx.x < n) bs[threadIdx.x] = batch[r0 + threadIdx.x];
  __syncthreads();
  const float sc = sums[2 * C + c];
  const float sh = sums[3 * C + c];
  int   cur_g = bs[0];
  float mx = -3.4e38f, s = 0.f;
  for (int r = r0; r < r1; ++r) {
    const int g = bs[r - r0];
    if (g != cur_g) {
      pool_flush(z, cur_g, C, zoff, c, mx, s);
      mx = -3.4e38f; s = 0.f; cur_g = g;
    }
    const float v = hpre[(size_t)r * C + c] * sc + sh;
    H[(size_t)r * C + c] = f2b(v);
    mx = fmaxf(mx, v);
    s += v;
  }
  pool_flush(z, cur_g, C, zoff, c, mx, s);
}

__global__ void pool_finalize_kernel(float* __restrict__ z, const int* __restrict__ gptr,
                                     int C, int zoff) {
  int i = blockIdx.x * blockDim.x + threadIdx.x;
  if (i >= N_GRAPH * C) return;
  int g = i / C, c = i % C;
  int cnt = gptr[g + 1] - gptr[g];
  float* zg = z + (size_t)g * Z_DIM + zoff;
  unsigned key = __float_as_uint(zg[c]);
  key ^= (key & 0x80000000u) ? 0x80000000u : 0xFFFFFFFFu;
  float mx = __uint_as_float(key);
  float sum = zg[2 * C + c];
  zg[c]     = (cnt > 0) ? mx : 0.f;
  zg[C + c] = sum / (float)(cnt > 0 ? cnt : 1);
}

// ---------------- FC head: split-K fc1 + fused fc2/fc3/log_softmax ----------------
// Block = 1024 threads = 8 k-splits x 128 channels per graph.

__global__ __launch_bounds__(1024) void fc_kernel(const float* __restrict__ z,
                                                  const float* __restrict__ w1, const float* __restrict__ b1,
                                                  const float* __restrict__ w2, const float* __restrict__ b2,
                                                  const float* __restrict__ w3, const float* __restrict__ b3,
                                                  float* __restrict__ out) {
  __shared__ float zs[Z_DIM];
  __shared__ float part[8][128];
  __shared__ float h1s[128];
  __shared__ float red[128][2];
  __shared__ float y2[2];
  const int g  = blockIdx.x;
  const int t  = threadIdx.x;
  const int c  = t & 127;
  const int ks = t >> 7;                 // 0..7
  for (int i = t; i < Z_DIM; i += 1024) zs[i] = z[(size_t)g * Z_DIM + i];
  __syncthreads();

  constexpr int KCH = Z_DIM / 8;         // 288
  const int k0 = ks * KCH;
  float acc = 0.f;
#pragma unroll 4
  for (int k = k0; k < k0 + KCH; ++k) acc += zs[k] * w1[(size_t)k * 128 + c];
  part[ks][c] = acc;
  __syncthreads();

  if (t < 128) {
    float s = b1[t];
#pragma unroll
    for (int i = 0; i < 8; ++i) s += part[i][t];
    h1s[t] = fmaxf(s, 0.f);
  }
  __syncthreads();
  if (t < 128) {
    red[t][0] = h1s[t] * w2[t * 2 + 0];
    red[t][1] = h1s[t] * w2[t * 2 + 1];
  }
  __syncthreads();
  if (t < 2) {
    float s = b2[t];
    for (int k = 0; k < 128; ++k) s += red[k][t];
    y2[t] = fmaxf(s, 0.f);
  }
  __syncthreads();
  if (t == 0) {
    const float z0 = y2[0] * w3[0] + y2[1] * w3[2] + b3[0];
    const float z1 = y2[0] * w3[1] + y2[1] * w3[3] + b3[1];
    const float m  = fmaxf(z0, z1);
    const float lse = m + logf(expf(z0 - m) + expf(z1 - m));
    out[g * 2 + 0] = z0 - lse;
    out[g * 2 + 1] = z1 - lse;
  }
}

// ---------------- launch ----------------

extern "C" void kernel_launch(void* const* d_in, const int* in_sizes, int n_in,
                              void* d_out, int out_size, void* d_ws, size_t ws_size,
                              hipStream_t stream) {
  (void)in_sizes; (void)n_in; (void)out_size; (void)ws_size;
  const float* x        = (const float*)d_in[0];
  const int*   eidx     = (const int*)d_in[1];
  const int*   batch    = (const int*)d_in[2];
  const float* eattr    = (const float*)d_in[3];
  const float* w_rel1   = (const float*)d_in[4];
  const float* b_rel1   = (const float*)d_in[5];
  const float* w_root1  = (const float*)d_in[6];
  const float* w_rel2   = (const float*)d_in[7];
  const float* b_rel2   = (const float*)d_in[8];
  const float* w_root2  = (const float*)d_in[9];
  const float* w_rel3   = (const float*)d_in[10];
  const float* b_rel3   = (const float*)d_in[11];
  const float* w_root3  = (const float*)d_in[12];
  const float* gamma1   = (const float*)d_in[13];
  const float* beta1    = (const float*)d_in[14];
  const float* gamma2   = (const float*)d_in[15];
  const float* beta2    = (const float*)d_in[16];
  const float* gamma3   = (const float*)d_in[17];
  const float* beta3    = (const float*)d_in[18];
  const float* w_lin1   = (const float*)d_in[19];
  const float* b_lin1   = (const float*)d_in[20];
  const float* w_lin2   = (const float*)d_in[21];
  const float* b_lin2   = (const float*)d_in[22];
  const float* w_lin3   = (const float*)d_in[23];
  const float* b_lin3   = (const float*)d_in[24];

  const int* src = eidx;
  const int* dst = eidx + N_EDGES;
  float* outp = (float*)d_out;

  char* ws = (char*)d_ws;
  size_t off = 0;
  auto alloc = [&](size_t bytes) -> void* {
    void* p = ws + off;
    off += (bytes + 255) & ~(size_t)255;
    return p;
  };
  int*   rowptr = (int*)alloc((N_NODES + 1) * sizeof(int));
  int*   cursor = (int*)alloc(N_NODES * sizeof(int));
  int*   gptr   = (int*)alloc((N_GRAPH + 1) * sizeof(int));
  int*   gcnt   = (int*)alloc(N_GRAPH * sizeof(int));
  int*   part   = (int*)alloc(256 * sizeof(int));
  int*   part2  = (int*)alloc(256 * sizeof(int));
  int*   esrc   = (int*)alloc(N_EDGES * sizeof(int));
  float* eww    = (float*)alloc(N_EDGES * sizeof(float));
  float* sums   = (float*)alloc(4 * 384 * sizeof(float));
  float* zbuf   = (float*)alloc((size_t)N_GRAPH * Z_DIM * sizeof(float));
  unsigned short* xb   = (unsigned short*)alloc((size_t)M_PAD * 128 * 2);
  unsigned short* H1   = (unsigned short*)alloc((size_t)M_PAD * 128 * 2);
  unsigned short* H2   = (unsigned short*)alloc((size_t)M_PAD * 256 * 2);
  unsigned short* H3   = (unsigned short*)alloc((size_t)M_PAD * 384 * 2);
  unsigned short* aggb = (unsigned short*)alloc((size_t)M_PAD * 256 * 2);
  float* hpre = (float*)alloc((size_t)N_NODES * 384 * sizeof(float));
  unsigned short* wt1 = (unsigned short*)alloc((size_t)128 * 256 * 2);
  unsigned short* wt2 = (unsigned short*)alloc((size_t)256 * 256 * 2);
  unsigned short* wt3 = (unsigned short*)alloc((size_t)384 * 512 * 2);

  const int EB = (N_EDGES + 255) / 256;
  const int NB = (N_NODES + 255) / 256;
  const int RB = (N_NODES + 63) / 64;
  const int SB = (N_NODES + 1023) / 1024;

  // ---- CSR by dst ----
  hipMemsetAsync(cursor, 0, N_NODES * sizeof(int), stream);
  hist_kernel<<<EB, 256, 0, stream>>>(dst, cursor, N_EDGES);
  scan1_kernel<<<SB, 256, 0, stream>>>(cursor, rowptr, part, N_NODES);
  scan2_kernel<<<1, 256, 0, stream>>>(part, SB, rowptr + N_NODES);
  scan3_kernel<<<NB, 256, 0, stream>>>(rowptr, part, N_NODES);
  hipMemsetAsync(cursor, 0, N_NODES * sizeof(int), stream);
  bucket_kernel<<<EB, 256, 0, stream>>>(src, dst, eattr, rowptr, cursor, esrc, eww, N_EDGES);

  // ---- graph segment pointers ----
  hipMemsetAsync(gcnt, 0, N_GRAPH * sizeof(int), stream);
  hist_kernel<<<NB, 256, 0, stream>>>(batch, gcnt, N_NODES);
  scan1_kernel<<<1, 256, 0, stream>>>(gcnt, gptr, part2, N_GRAPH);
  scan2_kernel<<<1, 256, 0, stream>>>(part2, 1, gptr + N_GRAPH);

  // ---- prep ----
  hipMemsetAsync(zbuf, 0, (size_t)N_GRAPH * Z_DIM * sizeof(float), stream);
  cast_bf16_kernel<<<(N_NODES * 128 / 2 + 255) / 256, 256, 0, stream>>>(x, xb, N_NODES * 128 / 2);
  wt_build_kernel<<<128, 256, 0, stream>>>(w_rel1, w_root1, wt1, 128, 128);
  wt_build_kernel<<<256, 256, 0, stream>>>(w_rel2, w_root2, wt2, 128, 256);
  wt_build_kernel<<<384, 256, 0, stream>>>(w_rel3, w_root3, wt3, 256, 384);

  const int aggBlocks = (N_NODES * 64 + 255) / 256;
  const int MB = M_PAD / 128;

  // ---- layer 1: 128 -> 128 ----
  agg_bf16_kernel<128><<<aggBlocks, 256, 0, stream>>>(xb, rowptr, esrc, eww, aggb);
  hipMemsetAsync(sums, 0, 4 * 128 * sizeof(float), stream);
  gemm_mfma_kernel<<<dim3(MB, 1), 256, 0, stream>>>(aggb, xb, wt1, b_rel1, hpre, sums,
                                                    N_NODES, 128, 128);
  bn_finalize_kernel<<<1, 128, 0, stream>>>(sums, gamma1, beta1, N_NODES, 128);
  bn_apply_pool_kernel<<<dim3(RB, 1), 128, 0, stream>>>(hpre, sums, H1, batch, zbuf,
                                                        N_NODES, 128, 0);
  pool_finalize_kernel<<<(N_GRAPH * 128 + 255) / 256, 256, 0, stream>>>(zbuf, gptr, 128, 0);

  // ---- layer 2: 128 -> 256 ----
  agg_bf16_kernel<128><<<aggBlocks, 256, 0, stream>>>(H1, rowptr, esrc, eww, aggb);
  hipMemsetAsync(sums, 0, 4 * 256 * sizeof(float), stream);
  gemm_mfma_kernel<<<dim3(MB, 2), 256, 0, stream>>>(aggb, H1, wt2, b_rel2, hpre, sums,
                                                    N_NODES, 128, 256);
  bn_finalize_kernel<<<1, 256, 0, stream>>>(sums, gamma2, beta2, N_NODES, 256);
  bn_apply_pool_kernel<<<dim3(RB, 2), 128, 0, stream>>>(hpre, sums, H2, batch, zbuf,
                                                        N_NODES, 256, 384);
  pool_finalize_kernel<<<(N_GRAPH * 256 + 255) / 256, 256, 0, stream>>>(zbuf, gptr, 256, 384);

  // ---- layer 3: 256 -> 384 ----
  agg_bf16_kernel<256><<<aggBlocks, 256, 0, stream>>>(H2, rowptr, esrc, eww, aggb);
  hipMemsetAsync(sums, 0, 4 * 384 * sizeof(float), stream);
  gemm_mfma_kernel<<<dim3(MB, 3), 256, 0, stream>>>(aggb, H2, wt3, b_rel3, hpre, sums,
                                                    N_NODES, 256, 384);
  bn_finalize_kernel<<<2, 256, 0, stream>>>(sums, gamma3, beta3, N_NODES, 384);
  bn_apply_pool_kernel<<<dim3(RB, 3), 128, 0, stream>>>(hpre, sums, H3, batch, zbuf,
                                                        N_NODES, 384, 1152);
  pool_finalize_kernel<<<(N_GRAPH * 384 + 255) / 256, 256, 0, stream>>>(zbuf, gptr, 384, 1152);

  // ---- FC head ----
  fc_kernel<<<N_GRAPH, 1024, 0, stream>>>(zbuf, w_lin1, b_lin1, w_lin2, b_lin2, w_lin3, b_lin3,
                                          outp);
}